// Round 6
// baseline (230.745 us; speedup 1.0000x reference)
//
#include <hip/hip_runtime.h>
#include <math.h>

#define KS_ 0.1803368801111244f   // 0.125 * log2(e)

typedef __attribute__((ext_vector_type(8))) short bf16x8;
typedef __attribute__((ext_vector_type(4))) short bf16x4;
typedef __attribute__((ext_vector_type(4))) float f32x4;

__device__ inline short f2bf(float f) {
  unsigned u = __builtin_bit_cast(unsigned, f);
  u += 0x7fff + ((u >> 16) & 1);
  return (short)(u >> 16);
}

// async global->LDS 16B DMA (dest = wave-uniform base + lane*16)
__device__ inline void gload16(const short* g, short* l) {
  __builtin_amdgcn_global_load_lds(
      (const __attribute__((address_space(1))) void*)g,
      (__attribute__((address_space(3))) void*)l, 16, 0, 0);
}

// ---------- helper: 32x32 transpose tile of W [K][N] -> WT bf16 [N][K] ----------
__device__ inline void wt_tile(const float* __restrict__ W, short* __restrict__ WT,
                               int K, int N, int bx, int by, int t, float (*tile)[33]) {
  int n0 = bx * 32, k0 = by * 32;
  int tx = t & 31, ty = t >> 5;
#pragma unroll
  for (int r = 0; r < 32; r += 8)
    tile[ty + r][tx] = W[(size_t)(k0 + ty + r) * N + n0 + tx];
  __syncthreads();
#pragma unroll
  for (int r = 0; r < 32; r += 8)
    WT[(size_t)(n0 + ty + r) * K + k0 + tx] = f2bf(tile[tx][ty + r]);
}

// ---------- mega prep: x-transpose + all 5 weight transposes in one launch ----------
__global__ __launch_bounds__(256) void k_prep_all(const float* __restrict__ x, float* __restrict__ xt,
                                                  short* __restrict__ xtbf,
                                                  const float* __restrict__ Wq, const float* __restrict__ Wkv,
                                                  const float* __restrict__ Wout, const float* __restrict__ Wff1,
                                                  const float* __restrict__ Wff2,
                                                  short* __restrict__ WqkvT, short* __restrict__ WoutT,
                                                  short* __restrict__ Wff1T, short* __restrict__ Wff2T) {
  __shared__ float tile[32][33];
  int bid = blockIdx.x, t = threadIdx.x;
  if (bid < 8192) {
    wt_tile(Wout, WoutT, 4096, 2048, bid & 63, bid >> 6, t, tile);
  } else if (bid < 9216) {
    int r = bid - 8192;
    int bx = r & 7, by = (r >> 3) & 7, bm = r >> 6;
    int b = bm >> 3, m = bm & 7;
    int d0 = bx * 32, n0 = by * 32;
    int tx = t & 31, ty = t >> 5;
#pragma unroll
    for (int rr = 0; rr < 32; rr += 8) {
      int d = d0 + ty + rr, n = n0 + tx;
      tile[ty + rr][tx] = x[((size_t)(b * 256 + d) * 8 + m) * 256 + n];
    }
    __syncthreads();
#pragma unroll
    for (int rr = 0; rr < 32; rr += 8) {
      int n = n0 + ty + rr, d = d0 + tx;
      float v = tile[tx][ty + rr];
      size_t idx = ((size_t)(b * 256 + n) * 8 + m) * 256 + d;
      xt[idx] = v;
      xtbf[idx] = f2bf(v);
    }
  } else if (bid < 9344) {
    int r = bid - 9216;
    wt_tile(Wq, WqkvT, 256, 512, r & 15, r >> 4, t, tile);
  } else if (bid < 9600) {
    int r = bid - 9344;
    wt_tile(Wkv, WqkvT + 131072, 256, 1024, r & 31, r >> 5, t, tile);
  } else if (bid < 10112) {
    int r = bid - 9600;
    wt_tile(Wff1, Wff1T, 256, 2048, r & 63, r >> 6, t, tile);
  } else {
    int r = bid - 10112;
    wt_tile(Wff2, Wff2T, 1024, 256, r & 7, r >> 3, t, tile);
  }
}

// ---------- fused qkv GEMM with fragment-layout epilogue ----------
// A = xt_bf [4096][256]; Bt = WqkvT [1536][256]. grid (24, 64).
__global__ __launch_bounds__(256) void k_gemm_qkv(const short* __restrict__ A, const short* __restrict__ Bt,
                                                  short* __restrict__ qfrag, short* __restrict__ kfrag,
                                                  short* __restrict__ vfrag) {
  __shared__ short As[2][2048];
  __shared__ short Bs[2][2048];
  __shared__ short Cs[64 * 72];
  int t = threadIdx.x;
  int bx = blockIdx.x, by = blockIdx.y;
  int sel = bx >> 3, h = bx & 7;
  int row0 = by * 64, col0 = bx * 64;
  int b = by >> 5, n0 = (by * 8) & 255;
  int bh = b * 8 + h;
  int w = t >> 6, lane = t & 63, quad = lane >> 4, l16 = lane & 15;
  int wr = w >> 1, wc = w & 1;
  int r = t >> 2;
  int cs = ((t & 3) ^ ((r >> 1) & 3)) * 8;
  const short* Ag = A + (size_t)(row0 + r) * 256 + cs;
  const short* Bg = Bt + (size_t)(col0 + r) * 256 + cs;
  int sw = (l16 >> 1) & 3;
  int chk = (quad ^ sw) * 8;
  int aoff[2], boff[2];
#pragma unroll
  for (int rf = 0; rf < 2; rf++) {
    aoff[rf] = (wr * 32 + rf * 16 + l16) * 32 + chk;
    boff[rf] = (wc * 32 + rf * 16 + l16) * 32 + chk;
  }
  f32x4 acc[2][2] = {{{0,0,0,0},{0,0,0,0}},{{0,0,0,0},{0,0,0,0}}};
  gload16(Ag, &As[0][w * 512]);
  gload16(Bg, &Bs[0][w * 512]);
  __syncthreads();
  int buf = 0;
  for (int k0 = 0; k0 < 256; k0 += 32) {
    int nb = buf ^ 1;
    if (k0 + 32 < 256) {
      gload16(Ag + k0 + 32, &As[nb][w * 512]);
      gload16(Bg + k0 + 32, &Bs[nb][w * 512]);
    }
    bf16x8 af[2], bf[2];
#pragma unroll
    for (int rf = 0; rf < 2; rf++) af[rf] = *(const bf16x8*)&As[buf][aoff[rf]];
#pragma unroll
    for (int cf = 0; cf < 2; cf++) bf[cf] = *(const bf16x8*)&Bs[buf][boff[cf]];
#pragma unroll
    for (int rf = 0; rf < 2; rf++)
#pragma unroll
      for (int cf = 0; cf < 2; cf++)
        acc[rf][cf] = __builtin_amdgcn_mfma_f32_16x16x32_bf16(af[rf], bf[cf], acc[rf][cf], 0, 0, 0);
    __syncthreads();
    buf = nb;
  }
  // ---- stage result tile to LDS as bf16 ----
  if (sel < 2) {
#pragma unroll
    for (int rf = 0; rf < 2; rf++)
#pragma unroll
      for (int cf = 0; cf < 2; cf++) {
        int col = wc * 32 + cf * 16 + l16;
#pragma unroll
        for (int rr = 0; rr < 4; rr++)
          Cs[(wr * 32 + rf * 16 + quad * 4 + rr) * 72 + col] = f2bf(acc[rf][cf][rr]);
      }
  } else {
#pragma unroll
    for (int rf = 0; rf < 2; rf++)
#pragma unroll
      for (int cf = 0; cf < 2; cf++) {
        int col = wc * 32 + cf * 16 + l16;
        bf16x4 pk;
#pragma unroll
        for (int rr = 0; rr < 4; rr++) pk[rr] = f2bf(acc[rf][cf][rr]);
        *(bf16x4*)&Cs[col * 72 + wr * 32 + rf * 16 + quad * 4] = pk;
      }
  }
  __syncthreads();
  // ---- fragment-order global writes ----
  if (sel < 2) {
    short* dst = sel ? kfrag : qfrag;
    int it = n0 >> 4, l16b = n0 & 8;
#pragma unroll
    for (int cidx = 0; cidx < 2; cidx++) {
      int chunk = t + cidx * 256;        // bits: m[8:6] ks[5] q2[4:3] n[2:0]
      int m = chunk >> 6, ks2 = (chunk >> 5) & 1, q2 = (chunk >> 3) & 3, n = chunk & 7;
      bf16x8 val = *(const bf16x8*)&Cs[(n * 8 + m) * 72 + ks2 * 32 + q2 * 8];
      size_t off = ((size_t)(bh * 128 + m * 16 + it) * 2 + ks2) * 512 + (q2 * 16 + l16b + n) * 8;
      *(bf16x8*)(dst + off) = val;
    }
  } else {
    int jc = n0 >> 5, jf = (n0 >> 4) & 1, qbase = (n0 & 8) >> 2;   // quad base 0 or 2
#pragma unroll
    for (int cidx = 0; cidx < 2; cidx++) {
      int chunk = t + cidx * 256;        // bits: qd[8] m0[7:6] dt[5:4] l16[3:0]
      int qd = chunk >> 8, m0 = (chunk >> 6) & 3, dtt = (chunk >> 4) & 3, l16c = chunk & 15;
      int d = dtt * 16 + l16c;
      unsigned u[4];
#pragma unroll
      for (int e3 = 0; e3 < 4; e3++)
        u[e3] = *(const unsigned*)&Cs[d * 72 + qd * 32 + e3 * 8 + 2 * m0];
      uint4 pv;
      pv.x = __builtin_amdgcn_perm(u[1], u[0], 0x05040100u);
      pv.y = __builtin_amdgcn_perm(u[3], u[2], 0x05040100u);
      pv.z = __builtin_amdgcn_perm(u[1], u[0], 0x07060302u);
      pv.w = __builtin_amdgcn_perm(u[3], u[2], 0x07060302u);
      int quad2 = qbase + qd;
      size_t cid = (((size_t)(bh * 8 + jc) * 4 + m0) * 4 + dtt) * 2 + jf;
      *(bf16x8*)(vfrag + cid * 512 + (quad2 * 16 + l16c) * 8) = __builtin_bit_cast(bf16x8, pv);
    }
  }
}

// ---------- Wout GEMM: 128-row x 64-col tiles, split-K; grid (N/64, M/128, K/Ks) ----------
__global__ __launch_bounds__(256) void k_gemm_w128(const short* __restrict__ A, const short* __restrict__ Bt,
                                                   const float* __restrict__ bias, float* __restrict__ C,
                                                   int M, int N, int K, int Ks) {
  __shared__ short As[2][4096];
  __shared__ short Bs[2][2048];
  int t = threadIdx.x;
  int row0 = blockIdx.y * 128, col0 = blockIdx.x * 64;
  int kp = blockIdx.z;
  int kbeg = kp * Ks, kend = kbeg + Ks;
  int w = t >> 6, lane = t & 63, quad = lane >> 4, l16 = lane & 15;
  int wr = w >> 1, wc = w & 1;
  int rs = t >> 2;
  int cs = ((t & 3) ^ ((rs >> 1) & 3)) * 8;
  const short* Ag = A + (size_t)(row0 + rs) * K + cs;
  const short* Bg = Bt + (size_t)(col0 + rs) * K + cs;
  size_t rskip = (size_t)64 * K;
  int chk = (quad ^ ((l16 >> 1) & 3)) * 8;
  int aoff[4], boff[2];
#pragma unroll
  for (int f = 0; f < 4; f++) aoff[f] = (wr * 64 + f * 16 + l16) * 32 + chk;
#pragma unroll
  for (int f = 0; f < 2; f++) boff[f] = (wc * 32 + f * 16 + l16) * 32 + chk;
  f32x4 acc[4][2];
#pragma unroll
  for (int i = 0; i < 4; i++)
#pragma unroll
    for (int j = 0; j < 2; j++) acc[i][j] = (f32x4){0, 0, 0, 0};
  int ld0 = w * 512;
  gload16(Ag + kbeg, &As[0][ld0]);
  gload16(Ag + rskip + kbeg, &As[0][2048 + ld0]);
  gload16(Bg + kbeg, &Bs[0][ld0]);
  __syncthreads();
  int buf = 0;
  for (int k0 = kbeg; k0 < kend; k0 += 32) {
    int nb = buf ^ 1;
    if (k0 + 32 < kend) {
      gload16(Ag + k0 + 32, &As[nb][ld0]);
      gload16(Ag + rskip + k0 + 32, &As[nb][2048 + ld0]);
      gload16(Bg + k0 + 32, &Bs[nb][ld0]);
    }
    bf16x8 af[4], bf[2];
#pragma unroll
    for (int f = 0; f < 4; f++) af[f] = *(const bf16x8*)&As[buf][aoff[f]];
#pragma unroll
    for (int f = 0; f < 2; f++) bf[f] = *(const bf16x8*)&Bs[buf][boff[f]];
#pragma unroll
    for (int i = 0; i < 4; i++)
#pragma unroll
      for (int j = 0; j < 2; j++)
        acc[i][j] = __builtin_amdgcn_mfma_f32_16x16x32_bf16(af[i], bf[j], acc[i][j], 0, 0, 0);
    __syncthreads();
    buf = nb;
  }
  float* Cp = C + (size_t)kp * M * N;
  bool dob = (bias && kp == 0);
#pragma unroll
  for (int i = 0; i < 4; i++)
#pragma unroll
    for (int j = 0; j < 2; j++) {
      int col = col0 + wc * 32 + j * 16 + l16;
      float vb = dob ? bias[col] : 0.0f;
#pragma unroll
      for (int rr = 0; rr < 4; rr++) {
        int row = row0 + wr * 64 + i * 16 + quad * 4 + rr;
        Cp[(size_t)row * N + col] = acc[i][j][rr] + vb;
      }
    }
}

// ---------- bf16 MFMA 64x64 GEMM with split-K (ff2) ----------
__global__ __launch_bounds__(256) void k_gemm_bf(const short* __restrict__ A, const short* __restrict__ Bt,
                                                 const float* __restrict__ bias, float* __restrict__ C,
                                                 int M, int N, int K, int Ks) {
  __shared__ short As[2][2048];
  __shared__ short Bs[2][2048];
  int t = threadIdx.x;
  int row0 = blockIdx.y * 64, col0 = blockIdx.x * 64;
  int kp = blockIdx.z;
  int kbeg = kp * Ks, kend = kbeg + Ks;
  int w = t >> 6, lane = t & 63, quad = lane >> 4, l16 = lane & 15;
  int wr = w >> 1, wc = w & 1;
  int r = t >> 2;
  int cs = ((t & 3) ^ ((r >> 1) & 3)) * 8;
  const short* Ag = A + (size_t)(row0 + r) * K + cs;
  const short* Bg = Bt + (size_t)(col0 + r) * K + cs;
  int sw = (l16 >> 1) & 3;
  int chk = (quad ^ sw) * 8;
  int aoff[2], boff[2];
#pragma unroll
  for (int rf = 0; rf < 2; rf++) {
    aoff[rf] = (wr * 32 + rf * 16 + l16) * 32 + chk;
    boff[rf] = (wc * 32 + rf * 16 + l16) * 32 + chk;
  }
  f32x4 acc[2][2] = {{{0,0,0,0},{0,0,0,0}},{{0,0,0,0},{0,0,0,0}}};
  gload16(Ag + kbeg, &As[0][w * 512]);
  gload16(Bg + kbeg, &Bs[0][w * 512]);
  __syncthreads();
  int buf = 0;
  for (int k0 = kbeg; k0 < kend; k0 += 32) {
    int nb = buf ^ 1;
    if (k0 + 32 < kend) {
      gload16(Ag + k0 + 32, &As[nb][w * 512]);
      gload16(Bg + k0 + 32, &Bs[nb][w * 512]);
    }
    bf16x8 af[2], bf[2];
#pragma unroll
    for (int rf = 0; rf < 2; rf++) af[rf] = *(const bf16x8*)&As[buf][aoff[rf]];
#pragma unroll
    for (int cf = 0; cf < 2; cf++) bf[cf] = *(const bf16x8*)&Bs[buf][boff[cf]];
#pragma unroll
    for (int rf = 0; rf < 2; rf++)
#pragma unroll
      for (int cf = 0; cf < 2; cf++)
        acc[rf][cf] = __builtin_amdgcn_mfma_f32_16x16x32_bf16(af[rf], bf[cf], acc[rf][cf], 0, 0, 0);
    __syncthreads();
    buf = nb;
  }
  float* Cp = C + (size_t)kp * M * N;
#pragma unroll
  for (int rf = 0; rf < 2; rf++)
#pragma unroll
    for (int cf = 0; cf < 2; cf++) {
      int col = col0 + wc * 32 + cf * 16 + l16;
      float vb = (bias && kp == 0) ? bias[col] : 0.0f;
#pragma unroll
      for (int rr = 0; rr < 4; rr++) {
        int row = row0 + wr * 32 + rf * 16 + quad * 4 + rr;
        Cp[(size_t)row * N + col] = acc[rf][cf][rr] + vb;
      }
    }
}

// ---------- fused ff1 GEMM + GEGLU ----------
__global__ __launch_bounds__(256) void k_ff1g(const short* __restrict__ A, const short* __restrict__ Bt,
                                              const float* __restrict__ bias, short* __restrict__ gg) {
  __shared__ short As[2][2048];
  __shared__ short Ba[2][2048];
  __shared__ short Bgs[2][2048];
  int t = threadIdx.x;
  int colA0 = blockIdx.x * 64, row0 = blockIdx.y * 64;
  int w = t >> 6, lane = t & 63, quad = lane >> 4, l16 = lane & 15;
  int wr = w >> 1, wc = w & 1;
  int r = t >> 2;
  int cs = ((t & 3) ^ ((r >> 1) & 3)) * 8;
  const short* Ag  = A + (size_t)(row0 + r) * 256 + cs;
  const short* Bpa = Bt + (size_t)(colA0 + r) * 256 + cs;
  const short* Bpg = Bt + (size_t)(1024 + colA0 + r) * 256 + cs;
  int sw = (l16 >> 1) & 3;
  int chk = (quad ^ sw) * 8;
  int aoff[2], boff[2];
#pragma unroll
  for (int rf = 0; rf < 2; rf++) {
    aoff[rf] = (wr * 32 + rf * 16 + l16) * 32 + chk;
    boff[rf] = (wc * 32 + rf * 16 + l16) * 32 + chk;
  }
  f32x4 za = {0, 0, 0, 0};
  f32x4 acc_a[2][2] = {{za, za}, {za, za}};
  f32x4 acc_g[2][2] = {{za, za}, {za, za}};
  gload16(Ag, &As[0][w * 512]);
  gload16(Bpa, &Ba[0][w * 512]);
  gload16(Bpg, &Bgs[0][w * 512]);
  __syncthreads();
  int buf = 0;
  for (int k0 = 0; k0 < 256; k0 += 32) {
    int nb = buf ^ 1;
    if (k0 + 32 < 256) {
      gload16(Ag + k0 + 32, &As[nb][w * 512]);
      gload16(Bpa + k0 + 32, &Ba[nb][w * 512]);
      gload16(Bpg + k0 + 32, &Bgs[nb][w * 512]);
    }
    bf16x8 af[2], ba[2], bg[2];
#pragma unroll
    for (int rf = 0; rf < 2; rf++) af[rf] = *(const bf16x8*)&As[buf][aoff[rf]];
#pragma unroll
    for (int cf = 0; cf < 2; cf++) {
      ba[cf] = *(const bf16x8*)&Ba[buf][boff[cf]];
      bg[cf] = *(const bf16x8*)&Bgs[buf][boff[cf]];
    }
#pragma unroll
    for (int rf = 0; rf < 2; rf++)
#pragma unroll
      for (int cf = 0; cf < 2; cf++) {
        acc_a[rf][cf] = __builtin_amdgcn_mfma_f32_16x16x32_bf16(af[rf], ba[cf], acc_a[rf][cf], 0, 0, 0);
        acc_g[rf][cf] = __builtin_amdgcn_mfma_f32_16x16x32_bf16(af[rf], bg[cf], acc_g[rf][cf], 0, 0, 0);
      }
    __syncthreads();
    buf = nb;
  }
#pragma unroll
  for (int rf = 0; rf < 2; rf++)
#pragma unroll
    for (int cf = 0; cf < 2; cf++) {
      int col = colA0 + wc * 32 + cf * 16 + l16;
      float ba_ = bias[col], bg_ = bias[1024 + col];
#pragma unroll
      for (int rr = 0; rr < 4; rr++) {
        int row = row0 + wr * 32 + rf * 16 + quad * 4 + rr;
        float a = acc_a[rf][cf][rr] + ba_;
        float g = acc_g[rf][cf][rr] + bg_;
        float ge = 0.5f * g * (1.0f + erff(g * 0.70710678118654752f));
        gg[(size_t)row * 1024 + col] = f2bf(a * ge);
      }
    }
}

// ---------- attention pass 1: 2 K-frags per wave; grid (ct2 16, mp 4, bh 16) ----------
__global__ __launch_bounds__(256) void k_attn_den5(const short* __restrict__ qfrag, const short* __restrict__ kfrag,
                                                   float* __restrict__ rdg) {
  int ct2 = blockIdx.x, mp = blockIdx.y, bh = blockIdx.z;
  int t = threadIdx.x;
  int w = t >> 6, lane = t & 63;
  int rt0 = ct2 * 8 + w * 2;
  bf16x8 bfr[2][2];
#pragma unroll
  for (int cf = 0; cf < 2; cf++)
#pragma unroll
    for (int ks = 0; ks < 2; ks++)
      bfr[cf][ks] = *(const bf16x8*)(kfrag + ((size_t)((bh * 128 + rt0 + cf) * 2 + ks)) * 512 + lane * 8);
  for (int mi = 0; mi < 2; mi++) {
    int m = mp * 2 + mi;
    float fa0 = 0.0f, fa1 = 0.0f;
#pragma unroll 4
    for (int it2 = 0; it2 < 16; it2++) {
      const short* ap = qfrag + ((size_t)((bh * 128 + m * 16 + it2) * 2)) * 512 + lane * 8;
      bf16x8 a0 = *(const bf16x8*)ap;
      bf16x8 a1 = *(const bf16x8*)(ap + 512);
      f32x4 c0 = {0, 0, 0, 0}, c1 = {0, 0, 0, 0};
      __builtin_amdgcn_s_setprio(1);
      c0 = __builtin_amdgcn_mfma_f32_16x16x32_bf16(a0, bfr[0][0], c0, 0, 0, 0);
      c0 = __builtin_amdgcn_mfma_f32_16x16x32_bf16(a1, bfr[0][1], c0, 0, 0, 0);
      c1 = __builtin_amdgcn_mfma_f32_16x16x32_bf16(a0, bfr[1][0], c1, 0, 0, 0);
      c1 = __builtin_amdgcn_mfma_f32_16x16x32_bf16(a1, bfr[1][1], c1, 0, 0, 0);
      __builtin_amdgcn_s_setprio(0);
#pragma unroll
      for (int rr = 0; rr < 4; rr++) {
        fa0 += __builtin_amdgcn_exp2f(c0[rr] * KS_);
        fa1 += __builtin_amdgcn_exp2f(c1[rr] * KS_);
      }
    }
    fa0 += __shfl_xor(fa0, 16); fa0 += __shfl_xor(fa0, 32);
    fa1 += __shfl_xor(fa1, 16); fa1 += __shfl_xor(fa1, 32);
    if (lane < 16) {
      rdg[(size_t)(bh * 8 + m) * 2048 + rt0 * 16 + lane] = -__builtin_amdgcn_logf(fa0);
      rdg[(size_t)(bh * 8 + m) * 2048 + (rt0 + 1) * 16 + lane] = -__builtin_amdgcn_logf(fa1);
    }
  }
}

// ---------- attention pass 2: 2 i-tiles/block + next-jc register prefetch; grid (z 8, itp 8, bh 16) ----------
__global__ __launch_bounds__(256) void k_attn_out6(const short* __restrict__ qfrag, const short* __restrict__ kfrag,
                                                   const short* __restrict__ vfrag, const float* __restrict__ rdg,
                                                   short* __restrict__ ao) {
  __shared__ float red[4 * 64 * 17];
  int z = blockIdx.x, itp = blockIdx.y, bh = blockIdx.z;
  int b = bh >> 3, h = bh & 7;
  int t = threadIdx.x, w = t >> 6, lane = t & 63, quad = lane >> 4, l16 = lane & 15;
  const float* rb = rdg + (size_t)bh * 16384;
  f32x4 z4 = {0, 0, 0, 0};
  bf16x8 qf[2][2][2];
#pragma unroll
  for (int iti = 0; iti < 2; iti++)
#pragma unroll
    for (int mm = 0; mm < 2; mm++)
#pragma unroll
      for (int ks = 0; ks < 2; ks++)
        qf[iti][mm][ks] = *(const bf16x8*)(qfrag +
            ((size_t)((bh * 128 + (2 * w + mm) * 16 + itp * 2 + iti) * 2 + ks)) * 512 + lane * 8);
  f32x4 acc[2][4];
#pragma unroll
  for (int iti = 0; iti < 2; iti++)
#pragma unroll
    for (int dt = 0; dt < 4; dt++) acc[iti][dt] = z4;
  bf16x8 vf[4][2], kf[2][2];
  float4 nv0[2], nv1[2];
#pragma unroll
  for (int dt = 0; dt < 4; dt++)
#pragma unroll
    for (int jf = 0; jf < 2; jf++)
      vf[dt][jf] = *(const bf16x8*)(vfrag + ((((size_t)(bh * 8 + 0) * 4 + w) * 4 + dt) * 2 + jf) * 512 + lane * 8);
#pragma unroll
  for (int jf = 0; jf < 2; jf++) {
    const short* kp = kfrag + ((size_t)((bh * 128 + z * 16 + 0 * 2 + jf) * 2)) * 512 + lane * 8;
    kf[jf][0] = *(const bf16x8*)kp;
    kf[jf][1] = *(const bf16x8*)(kp + 512);
    nv0[jf] = *(const float4*)(rb + (size_t)(2 * w) * 2048 + z * 256 + 0 * 32 + jf * 16 + quad * 4);
    nv1[jf] = *(const float4*)(rb + (size_t)(2 * w + 1) * 2048 + z * 256 + 0 * 32 + jf * 16 + quad * 4);
  }
  for (int jc = 0; jc < 8; jc++) {
    bf16x8 vfn[4][2], kfn[2][2];
    float4 nv0n[2], nv1n[2];
    if (jc < 7) {
      int jn = jc + 1;
#pragma unroll
      for (int dt = 0; dt < 4; dt++)
#pragma unroll
        for (int jf = 0; jf < 2; jf++)
          vfn[dt][jf] = *(const bf16x8*)(vfrag + ((((size_t)(bh * 8 + jn) * 4 + w) * 4 + dt) * 2 + jf) * 512 + lane * 8);
#pragma unroll
      for (int jf = 0; jf < 2; jf++) {
        const short* kp = kfrag + ((size_t)((bh * 128 + z * 16 + jn * 2 + jf) * 2)) * 512 + lane * 8;
        kfn[jf][0] = *(const bf16x8*)kp;
        kfn[jf][1] = *(const bf16x8*)(kp + 512);
        nv0n[jf] = *(const float4*)(rb + (size_t)(2 * w) * 2048 + z * 256 + jn * 32 + jf * 16 + quad * 4);
        nv1n[jf] = *(const float4*)(rb + (size_t)(2 * w + 1) * 2048 + z * 256 + jn * 32 + jf * 16 + quad * 4);
      }
    }
    float n0[2][4] = {{nv0[0].x, nv0[0].y, nv0[0].z, nv0[0].w}, {nv0[1].x, nv0[1].y, nv0[1].z, nv0[1].w}};
    float n1[2][4] = {{nv1[0].x, nv1[0].y, nv1[0].z, nv1[0].w}, {nv1[1].x, nv1[1].y, nv1[1].z, nv1[1].w}};
#pragma unroll
    for (int iti = 0; iti < 2; iti++) {
      f32x4 c[2][2] = {{z4, z4}, {z4, z4}};
      __builtin_amdgcn_s_setprio(1);
#pragma unroll
      for (int jf = 0; jf < 2; jf++)
#pragma unroll
        for (int mm = 0; mm < 2; mm++) {
          c[jf][mm] = __builtin_amdgcn_mfma_f32_16x16x32_bf16(kf[jf][0], qf[iti][mm][0], c[jf][mm], 0, 0, 0);
          c[jf][mm] = __builtin_amdgcn_mfma_f32_16x16x32_bf16(kf[jf][1], qf[iti][mm][1], c[jf][mm], 0, 0, 0);
        }
      __builtin_amdgcn_s_setprio(0);
      bf16x8 pf[2];
#pragma unroll
      for (int jf = 0; jf < 2; jf++) {
        unsigned u[8];
#pragma unroll
        for (int e = 0; e < 4; e++) {
          u[e]     = __builtin_bit_cast(unsigned, __builtin_amdgcn_exp2f(fmaf(c[jf][0][e], KS_, n0[jf][e]))) + 0x8000u;
          u[e + 4] = __builtin_bit_cast(unsigned, __builtin_amdgcn_exp2f(fmaf(c[jf][1][e], KS_, n1[jf][e]))) + 0x8000u;
        }
        uint4 pv;
        pv.x = __builtin_amdgcn_perm(u[1], u[0], 0x07060302u);
        pv.y = __builtin_amdgcn_perm(u[3], u[2], 0x07060302u);
        pv.z = __builtin_amdgcn_perm(u[5], u[4], 0x07060302u);
        pv.w = __builtin_amdgcn_perm(u[7], u[6], 0x07060302u);
        pf[jf] = __builtin_bit_cast(bf16x8, pv);
      }
      __builtin_amdgcn_s_setprio(1);
#pragma unroll
      for (int dt = 0; dt < 4; dt++)
#pragma unroll
        for (int jf = 0; jf < 2; jf++)
          acc[iti][dt] = __builtin_amdgcn_mfma_f32_16x16x32_bf16(vf[dt][jf], pf[jf], acc[iti][dt], 0, 0, 0);
      __builtin_amdgcn_s_setprio(0);
    }
    if (jc < 7) {
#pragma unroll
      for (int dt = 0; dt < 4; dt++)
#pragma unroll
        for (int jf = 0; jf < 2; jf++) vf[dt][jf] = vfn[dt][jf];
#pragma unroll
      for (int jf = 0; jf < 2; jf++) {
        kf[jf][0] = kfn[jf][0]; kf[jf][1] = kfn[jf][1];
        nv0[jf] = nv0n[jf]; nv1[jf] = nv1n[jf];
      }
    }
  }
  for (int iti = 0; iti < 2; iti++) {
#pragma unroll
    for (int dt = 0; dt < 4; dt++)
#pragma unroll
      for (int rr = 0; rr < 4; rr++)
        red[w * 1088 + (dt * 16 + quad * 4 + rr) * 17 + l16] = acc[iti][dt][rr];
    __syncthreads();
    {
      int i = t >> 4, dg = t & 15;
      float s[4] = {0, 0, 0, 0};
#pragma unroll
      for (int w2 = 0; w2 < 4; w2++)
#pragma unroll
        for (int r2 = 0; r2 < 4; r2++)
          s[r2] += red[w2 * 1088 + (dg * 4 + r2) * 17 + i];
      bf16x4 ov;
#pragma unroll
      for (int r2 = 0; r2 < 4; r2++) ov[r2] = f2bf(s[r2]);
      *(bf16x4*)(ao + (size_t)((b * 256 + itp * 32 + iti * 16 + i) * 8 + z) * 512 + h * 64 + dg * 4) = ov;
    }
    __syncthreads();
  }
}

// ---------- fused residual(np split-K partials) + layernorm; optional bf16 copy ----------
__global__ __launch_bounds__(256) void k_ln(const float* __restrict__ X, const float* __restrict__ P, int np,
                                            const float* __restrict__ g, const float* __restrict__ be,
                                            float* __restrict__ Y, short* __restrict__ Ybf) {
  __shared__ float sm[8];
  int row = blockIdx.x, t = threadIdx.x;
  int lane = t & 63, w = t >> 6;
  size_t base = (size_t)row * 256;
  float v = X[base + t];
  for (int p = 0; p < np; p++) v += P[(size_t)p * 1048576 + base + t];
  float s = v;
  s += __shfl_xor(s, 1); s += __shfl_xor(s, 2); s += __shfl_xor(s, 4);
  s += __shfl_xor(s, 8); s += __shfl_xor(s, 16); s += __shfl_xor(s, 32);
  if (lane == 0) sm[w] = s;
  __syncthreads();
  float mu = (sm[0] + sm[1] + sm[2] + sm[3]) * (1.0f / 256.0f);
  float dv = v - mu;
  float s2 = dv * dv;
  s2 += __shfl_xor(s2, 1); s2 += __shfl_xor(s2, 2); s2 += __shfl_xor(s2, 4);
  s2 += __shfl_xor(s2, 8); s2 += __shfl_xor(s2, 16); s2 += __shfl_xor(s2, 32);
  if (lane == 0) sm[4 + w] = s2;
  __syncthreads();
  float var = (sm[4] + sm[5] + sm[6] + sm[7]) * (1.0f / 256.0f);
  float rs = rsqrtf(var + 1e-5f);
  float res = dv * rs * g[t] + be[t];
  Y[base + t] = res;
  if (Ybf) Ybf[base + t] = f2bf(res);
}

extern "C" void kernel_launch(void* const* d_in, const int* in_sizes, int n_in,
                              void* d_out, int out_size, void* d_ws, size_t ws_size,
                              hipStream_t stream) {
  const float* x    = (const float*)d_in[0];
  const float* Wq   = (const float*)d_in[1];
  const float* Wkv  = (const float*)d_in[2];
  const float* Wout = (const float*)d_in[3];
  const float* bout = (const float*)d_in[4];
  const float* g1   = (const float*)d_in[5];
  const float* be1  = (const float*)d_in[6];
  const float* Wff1 = (const float*)d_in[7];
  const float* bff1 = (const float*)d_in[8];
  const float* Wff2 = (const float*)d_in[9];
  const float* bff2 = (const float*)d_in[10];
  const float* g2   = (const float*)d_in[11];
  const float* be2  = (const float*)d_in[12];
  float* out = (float*)d_out;
  float* w = (float*)d_ws;

  // fp32 zone
  float* xt   = w;              // 1,048,576
  float* part = w + 1048576;    // split-K partials (4 x 1M, two phases)
  float* y    = w + 9437184;    // 1,048,576
  float* rdg  = w + 11534336;   //   262,144  -log2(den), [bh*8+m][2048]
  // bf16 zone
  short* sb     = (short*)(w + 11796480);
  short* qfrag  = sb;                    // 2,097,152
  short* kfrag  = sb + 2097152;          // 2,097,152
  short* vfrag  = sb + 4194304;          // 2,097,152
  short* xt_bf  = sb + 6291456;          // 1,048,576
  short* ao_bf  = sb + 7340032;          // 2,097,152
  short* y_bf   = sb + 9437184;          // 1,048,576
  short* gg_bf  = sb + 10485760;         // 4,194,304
  short* WqkvT  = sb + 14680064;         //   393,216  [1536][256]
  short* WoutT  = sb + 15073280;         // 8,388,608
  short* Wff1T  = sb + 23461888;         //   524,288
  short* Wff2T  = sb + 23986176;         //   262,144

  k_prep_all<<<10368, 256, 0, stream>>>(x, xt, xt_bf, Wq, Wkv, Wout, Wff1, Wff2,
                                        WqkvT, WoutT, Wff1T, Wff2T);
  k_gemm_qkv<<<dim3(24, 64), 256, 0, stream>>>(xt_bf, WqkvT, qfrag, kfrag, vfrag);
  k_attn_den5<<<dim3(16, 4, 16), 256, 0, stream>>>(qfrag, kfrag, rdg);
  k_attn_out6<<<dim3(8, 8, 16), 256, 0, stream>>>(qfrag, kfrag, vfrag, rdg, ao_bf);
  k_gemm_w128<<<dim3(32, 4, 4), 256, 0, stream>>>(ao_bf, WoutT, bout, part, 512, 2048, 4096, 1024);
  k_ln<<<4096, 256, 0, stream>>>(xt, part, 4, g1, be1, y, y_bf);
  k_ff1g<<<dim3(16, 64), 256, 0, stream>>>(y_bf, Wff1T, bff1, gg_bf);
  k_gemm_bf<<<dim3(4, 64, 4), 256, 0, stream>>>(gg_bf, Wff2T, bff2, part, 4096, 256, 1024, 256);
  k_ln<<<4096, 256, 0, stream>>>(y, part, 4, g2, be2, out, nullptr);
}

// Round 7
// 215.317 us; speedup vs baseline: 1.0717x; 1.0717x over previous
//
#include <hip/hip_runtime.h>
#include <math.h>

#define KS_ 0.1803368801111244f   // 0.125 * log2(e)

typedef __attribute__((ext_vector_type(8))) short bf16x8;
typedef __attribute__((ext_vector_type(4))) short bf16x4;
typedef __attribute__((ext_vector_type(4))) float f32x4;

__device__ inline short f2bf(float f) {
  unsigned u = __builtin_bit_cast(unsigned, f);
  u += 0x7fff + ((u >> 16) & 1);
  return (short)(u >> 16);
}

// async global->LDS 16B DMA (dest = wave-uniform base + lane*16)
__device__ inline void gload16(const short* g, short* l) {
  __builtin_amdgcn_global_load_lds(
      (const __attribute__((address_space(1))) void*)g,
      (__attribute__((address_space(3))) void*)l, 16, 0, 0);
}

// ---------- helper: 32x32 transpose tile of W [K][N] -> WT bf16 [N][K] ----------
__device__ inline void wt_tile(const float* __restrict__ W, short* __restrict__ WT,
                               int K, int N, int bx, int by, int t, float (*tile)[33]) {
  int n0 = bx * 32, k0 = by * 32;
  int tx = t & 31, ty = t >> 5;
#pragma unroll
  for (int r = 0; r < 32; r += 8)
    tile[ty + r][tx] = W[(size_t)(k0 + ty + r) * N + n0 + tx];
  __syncthreads();
#pragma unroll
  for (int r = 0; r < 32; r += 8)
    WT[(size_t)(n0 + ty + r) * K + k0 + tx] = f2bf(tile[tx][ty + r]);
}

// ---------- mega prep: x-transpose + all 5 weight transposes in one launch ----------
__global__ __launch_bounds__(256) void k_prep_all(const float* __restrict__ x, float* __restrict__ xt,
                                                  short* __restrict__ xtbf,
                                                  const float* __restrict__ Wq, const float* __restrict__ Wkv,
                                                  const float* __restrict__ Wout, const float* __restrict__ Wff1,
                                                  const float* __restrict__ Wff2,
                                                  short* __restrict__ WqkvT, short* __restrict__ WoutT,
                                                  short* __restrict__ Wff1T, short* __restrict__ Wff2T) {
  __shared__ float tile[32][33];
  int bid = blockIdx.x, t = threadIdx.x;
  if (bid < 8192) {
    wt_tile(Wout, WoutT, 4096, 2048, bid & 63, bid >> 6, t, tile);
  } else if (bid < 9216) {
    int r = bid - 8192;
    int bx = r & 7, by = (r >> 3) & 7, bm = r >> 6;
    int b = bm >> 3, m = bm & 7;
    int d0 = bx * 32, n0 = by * 32;
    int tx = t & 31, ty = t >> 5;
#pragma unroll
    for (int rr = 0; rr < 32; rr += 8) {
      int d = d0 + ty + rr, n = n0 + tx;
      tile[ty + rr][tx] = x[((size_t)(b * 256 + d) * 8 + m) * 256 + n];
    }
    __syncthreads();
#pragma unroll
    for (int rr = 0; rr < 32; rr += 8) {
      int n = n0 + ty + rr, d = d0 + tx;
      float v = tile[tx][ty + rr];
      size_t idx = ((size_t)(b * 256 + n) * 8 + m) * 256 + d;
      xt[idx] = v;
      xtbf[idx] = f2bf(v);
    }
  } else if (bid < 9344) {
    int r = bid - 9216;
    wt_tile(Wq, WqkvT, 256, 512, r & 15, r >> 4, t, tile);
  } else if (bid < 9600) {
    int r = bid - 9344;
    wt_tile(Wkv, WqkvT + 131072, 256, 1024, r & 31, r >> 5, t, tile);
  } else if (bid < 10112) {
    int r = bid - 9600;
    wt_tile(Wff1, Wff1T, 256, 2048, r & 63, r >> 6, t, tile);
  } else {
    int r = bid - 10112;
    wt_tile(Wff2, Wff2T, 1024, 256, r & 7, r >> 3, t, tile);
  }
}

// ---------- fused qkv GEMM with fragment-layout epilogue ----------
// A = xt_bf [4096][256]; Bt = WqkvT [1536][256]. grid (24, 64).
__global__ __launch_bounds__(256) void k_gemm_qkv(const short* __restrict__ A, const short* __restrict__ Bt,
                                                  short* __restrict__ qfrag, short* __restrict__ kfrag,
                                                  short* __restrict__ vfrag) {
  __shared__ short As[2][2048];
  __shared__ short Bs[2][2048];
  __shared__ short Cs[64 * 72];
  int t = threadIdx.x;
  int bx = blockIdx.x, by = blockIdx.y;
  int sel = bx >> 3, h = bx & 7;
  int row0 = by * 64, col0 = bx * 64;
  int b = by >> 5, n0 = (by * 8) & 255;
  int bh = b * 8 + h;
  int w = t >> 6, lane = t & 63, quad = lane >> 4, l16 = lane & 15;
  int wr = w >> 1, wc = w & 1;
  int r = t >> 2;
  int cs = ((t & 3) ^ ((r >> 1) & 3)) * 8;
  const short* Ag = A + (size_t)(row0 + r) * 256 + cs;
  const short* Bg = Bt + (size_t)(col0 + r) * 256 + cs;
  int sw = (l16 >> 1) & 3;
  int chk = (quad ^ sw) * 8;
  int aoff[2], boff[2];
#pragma unroll
  for (int rf = 0; rf < 2; rf++) {
    aoff[rf] = (wr * 32 + rf * 16 + l16) * 32 + chk;
    boff[rf] = (wc * 32 + rf * 16 + l16) * 32 + chk;
  }
  f32x4 acc[2][2] = {{{0,0,0,0},{0,0,0,0}},{{0,0,0,0},{0,0,0,0}}};
  gload16(Ag, &As[0][w * 512]);
  gload16(Bg, &Bs[0][w * 512]);
  __syncthreads();
  int buf = 0;
  for (int k0 = 0; k0 < 256; k0 += 32) {
    int nb = buf ^ 1;
    if (k0 + 32 < 256) {
      gload16(Ag + k0 + 32, &As[nb][w * 512]);
      gload16(Bg + k0 + 32, &Bs[nb][w * 512]);
    }
    bf16x8 af[2], bf[2];
#pragma unroll
    for (int rf = 0; rf < 2; rf++) af[rf] = *(const bf16x8*)&As[buf][aoff[rf]];
#pragma unroll
    for (int cf = 0; cf < 2; cf++) bf[cf] = *(const bf16x8*)&Bs[buf][boff[cf]];
#pragma unroll
    for (int rf = 0; rf < 2; rf++)
#pragma unroll
      for (int cf = 0; cf < 2; cf++)
        acc[rf][cf] = __builtin_amdgcn_mfma_f32_16x16x32_bf16(af[rf], bf[cf], acc[rf][cf], 0, 0, 0);
    __syncthreads();
    buf = nb;
  }
  // ---- stage result tile to LDS as bf16 ----
  if (sel < 2) {
#pragma unroll
    for (int rf = 0; rf < 2; rf++)
#pragma unroll
      for (int cf = 0; cf < 2; cf++) {
        int col = wc * 32 + cf * 16 + l16;
#pragma unroll
        for (int rr = 0; rr < 4; rr++)
          Cs[(wr * 32 + rf * 16 + quad * 4 + rr) * 72 + col] = f2bf(acc[rf][cf][rr]);
      }
  } else {
#pragma unroll
    for (int rf = 0; rf < 2; rf++)
#pragma unroll
      for (int cf = 0; cf < 2; cf++) {
        int col = wc * 32 + cf * 16 + l16;
        bf16x4 pk;
#pragma unroll
        for (int rr = 0; rr < 4; rr++) pk[rr] = f2bf(acc[rf][cf][rr]);
        *(bf16x4*)&Cs[col * 72 + wr * 32 + rf * 16 + quad * 4] = pk;
      }
  }
  __syncthreads();
  // ---- fragment-order global writes ----
  if (sel < 2) {
    short* dst = sel ? kfrag : qfrag;
    int it = n0 >> 4, l16b = n0 & 8;
#pragma unroll
    for (int cidx = 0; cidx < 2; cidx++) {
      int chunk = t + cidx * 256;        // bits: m[8:6] ks[5] q2[4:3] n[2:0]
      int m = chunk >> 6, ks2 = (chunk >> 5) & 1, q2 = (chunk >> 3) & 3, n = chunk & 7;
      bf16x8 val = *(const bf16x8*)&Cs[(n * 8 + m) * 72 + ks2 * 32 + q2 * 8];
      size_t off = ((size_t)(bh * 128 + m * 16 + it) * 2 + ks2) * 512 + (q2 * 16 + l16b + n) * 8;
      *(bf16x8*)(dst + off) = val;
    }
  } else {
    int jc = n0 >> 5, jf = (n0 >> 4) & 1, qbase = (n0 & 8) >> 2;   // quad base 0 or 2
#pragma unroll
    for (int cidx = 0; cidx < 2; cidx++) {
      int chunk = t + cidx * 256;        // bits: qd[8] m0[7:6] dt[5:4] l16[3:0]
      int qd = chunk >> 8, m0 = (chunk >> 6) & 3, dtt = (chunk >> 4) & 3, l16c = chunk & 15;
      int d = dtt * 16 + l16c;
      unsigned u[4];
#pragma unroll
      for (int e3 = 0; e3 < 4; e3++)
        u[e3] = *(const unsigned*)&Cs[d * 72 + qd * 32 + e3 * 8 + 2 * m0];
      uint4 pv;
      pv.x = __builtin_amdgcn_perm(u[1], u[0], 0x05040100u);
      pv.y = __builtin_amdgcn_perm(u[3], u[2], 0x05040100u);
      pv.z = __builtin_amdgcn_perm(u[1], u[0], 0x07060302u);
      pv.w = __builtin_amdgcn_perm(u[3], u[2], 0x07060302u);
      int quad2 = qbase + qd;
      size_t cid = (((size_t)(bh * 8 + jc) * 4 + m0) * 4 + dtt) * 2 + jf;
      *(bf16x8*)(vfrag + cid * 512 + (quad2 * 16 + l16c) * 8) = __builtin_bit_cast(bf16x8, pv);
    }
  }
}

// ---------- bf16 MFMA GEMM with split-K; global_load_lds double-buffered main loop ----------
__global__ __launch_bounds__(256) void k_gemm_bf(const short* __restrict__ A, const short* __restrict__ Bt,
                                                 const float* __restrict__ bias, float* __restrict__ C,
                                                 int M, int N, int K, int Ks) {
  __shared__ short As[2][2048];
  __shared__ short Bs[2][2048];
  int t = threadIdx.x;
  int row0 = blockIdx.y * 64, col0 = blockIdx.x * 64;
  int kp = blockIdx.z;
  int kbeg = kp * Ks, kend = kbeg + Ks;
  int w = t >> 6, lane = t & 63, quad = lane >> 4, l16 = lane & 15;
  int wr = w >> 1, wc = w & 1;
  int r = t >> 2;
  int cs = ((t & 3) ^ ((r >> 1) & 3)) * 8;
  const short* Ag = A + (size_t)(row0 + r) * K + cs;
  const short* Bg = Bt + (size_t)(col0 + r) * K + cs;
  int sw = (l16 >> 1) & 3;
  int chk = (quad ^ sw) * 8;
  int aoff[2], boff[2];
#pragma unroll
  for (int rf = 0; rf < 2; rf++) {
    aoff[rf] = (wr * 32 + rf * 16 + l16) * 32 + chk;
    boff[rf] = (wc * 32 + rf * 16 + l16) * 32 + chk;
  }
  f32x4 acc[2][2] = {{{0,0,0,0},{0,0,0,0}},{{0,0,0,0},{0,0,0,0}}};
  gload16(Ag + kbeg, &As[0][w * 512]);
  gload16(Bg + kbeg, &Bs[0][w * 512]);
  __syncthreads();
  int buf = 0;
  for (int k0 = kbeg; k0 < kend; k0 += 32) {
    int nb = buf ^ 1;
    if (k0 + 32 < kend) {
      gload16(Ag + k0 + 32, &As[nb][w * 512]);
      gload16(Bg + k0 + 32, &Bs[nb][w * 512]);
    }
    bf16x8 af[2], bf[2];
#pragma unroll
    for (int rf = 0; rf < 2; rf++) af[rf] = *(const bf16x8*)&As[buf][aoff[rf]];
#pragma unroll
    for (int cf = 0; cf < 2; cf++) bf[cf] = *(const bf16x8*)&Bs[buf][boff[cf]];
#pragma unroll
    for (int rf = 0; rf < 2; rf++)
#pragma unroll
      for (int cf = 0; cf < 2; cf++)
        acc[rf][cf] = __builtin_amdgcn_mfma_f32_16x16x32_bf16(af[rf], bf[cf], acc[rf][cf], 0, 0, 0);
    __syncthreads();
    buf = nb;
  }
  float* Cp = C + (size_t)kp * M * N;
#pragma unroll
  for (int rf = 0; rf < 2; rf++)
#pragma unroll
    for (int cf = 0; cf < 2; cf++) {
      int col = col0 + wc * 32 + cf * 16 + l16;
      float vb = (bias && kp == 0) ? bias[col] : 0.0f;
#pragma unroll
      for (int rr = 0; rr < 4; rr++) {
        int row = row0 + wr * 32 + rf * 16 + quad * 4 + rr;
        Cp[(size_t)row * N + col] = acc[rf][cf][rr] + vb;
      }
    }
}

// ---------- fused ff1 GEMM + GEGLU ----------
__global__ __launch_bounds__(256) void k_ff1g(const short* __restrict__ A, const short* __restrict__ Bt,
                                              const float* __restrict__ bias, short* __restrict__ gg) {
  __shared__ short As[2][2048];
  __shared__ short Ba[2][2048];
  __shared__ short Bgs[2][2048];
  int t = threadIdx.x;
  int colA0 = blockIdx.x * 64, row0 = blockIdx.y * 64;
  int w = t >> 6, lane = t & 63, quad = lane >> 4, l16 = lane & 15;
  int wr = w >> 1, wc = w & 1;
  int r = t >> 2;
  int cs = ((t & 3) ^ ((r >> 1) & 3)) * 8;
  const short* Ag  = A + (size_t)(row0 + r) * 256 + cs;
  const short* Bpa = Bt + (size_t)(colA0 + r) * 256 + cs;
  const short* Bpg = Bt + (size_t)(1024 + colA0 + r) * 256 + cs;
  int sw = (l16 >> 1) & 3;
  int chk = (quad ^ sw) * 8;
  int aoff[2], boff[2];
#pragma unroll
  for (int rf = 0; rf < 2; rf++) {
    aoff[rf] = (wr * 32 + rf * 16 + l16) * 32 + chk;
    boff[rf] = (wc * 32 + rf * 16 + l16) * 32 + chk;
  }
  f32x4 za = {0, 0, 0, 0};
  f32x4 acc_a[2][2] = {{za, za}, {za, za}};
  f32x4 acc_g[2][2] = {{za, za}, {za, za}};
  gload16(Ag, &As[0][w * 512]);
  gload16(Bpa, &Ba[0][w * 512]);
  gload16(Bpg, &Bgs[0][w * 512]);
  __syncthreads();
  int buf = 0;
  for (int k0 = 0; k0 < 256; k0 += 32) {
    int nb = buf ^ 1;
    if (k0 + 32 < 256) {
      gload16(Ag + k0 + 32, &As[nb][w * 512]);
      gload16(Bpa + k0 + 32, &Ba[nb][w * 512]);
      gload16(Bpg + k0 + 32, &Bgs[nb][w * 512]);
    }
    bf16x8 af[2], ba[2], bg[2];
#pragma unroll
    for (int rf = 0; rf < 2; rf++) af[rf] = *(const bf16x8*)&As[buf][aoff[rf]];
#pragma unroll
    for (int cf = 0; cf < 2; cf++) {
      ba[cf] = *(const bf16x8*)&Ba[buf][boff[cf]];
      bg[cf] = *(const bf16x8*)&Bgs[buf][boff[cf]];
    }
#pragma unroll
    for (int rf = 0; rf < 2; rf++)
#pragma unroll
      for (int cf = 0; cf < 2; cf++) {
        acc_a[rf][cf] = __builtin_amdgcn_mfma_f32_16x16x32_bf16(af[rf], ba[cf], acc_a[rf][cf], 0, 0, 0);
        acc_g[rf][cf] = __builtin_amdgcn_mfma_f32_16x16x32_bf16(af[rf], bg[cf], acc_g[rf][cf], 0, 0, 0);
      }
    __syncthreads();
    buf = nb;
  }
#pragma unroll
  for (int rf = 0; rf < 2; rf++)
#pragma unroll
    for (int cf = 0; cf < 2; cf++) {
      int col = colA0 + wc * 32 + cf * 16 + l16;
      float ba_ = bias[col], bg_ = bias[1024 + col];
#pragma unroll
      for (int rr = 0; rr < 4; rr++) {
        int row = row0 + wr * 32 + rf * 16 + quad * 4 + rr;
        float a = acc_a[rf][cf][rr] + ba_;
        float g = acc_g[rf][cf][rr] + bg_;
        float ge = 0.5f * g * (1.0f + erff(g * 0.70710678118654752f));
        gg[(size_t)row * 1024 + col] = f2bf(a * ge);
      }
    }
}

// ---------- attention pass 1: 2 K-frags per wave; grid (ct2 16, mp 4, bh 16) ----------
__global__ __launch_bounds__(256) void k_attn_den5(const short* __restrict__ qfrag, const short* __restrict__ kfrag,
                                                   float* __restrict__ rdg) {
  int ct2 = blockIdx.x, mp = blockIdx.y, bh = blockIdx.z;
  int t = threadIdx.x;
  int w = t >> 6, lane = t & 63;
  int rt0 = ct2 * 8 + w * 2;
  bf16x8 bfr[2][2];
#pragma unroll
  for (int cf = 0; cf < 2; cf++)
#pragma unroll
    for (int ks = 0; ks < 2; ks++)
      bfr[cf][ks] = *(const bf16x8*)(kfrag + ((size_t)((bh * 128 + rt0 + cf) * 2 + ks)) * 512 + lane * 8);
  for (int mi = 0; mi < 2; mi++) {
    int m = mp * 2 + mi;
    float fa0 = 0.0f, fa1 = 0.0f;
#pragma unroll 4
    for (int it2 = 0; it2 < 16; it2++) {
      const short* ap = qfrag + ((size_t)((bh * 128 + m * 16 + it2) * 2)) * 512 + lane * 8;
      bf16x8 a0 = *(const bf16x8*)ap;
      bf16x8 a1 = *(const bf16x8*)(ap + 512);
      f32x4 c0 = {0, 0, 0, 0}, c1 = {0, 0, 0, 0};
      c0 = __builtin_amdgcn_mfma_f32_16x16x32_bf16(a0, bfr[0][0], c0, 0, 0, 0);
      c0 = __builtin_amdgcn_mfma_f32_16x16x32_bf16(a1, bfr[0][1], c0, 0, 0, 0);
      c1 = __builtin_amdgcn_mfma_f32_16x16x32_bf16(a0, bfr[1][0], c1, 0, 0, 0);
      c1 = __builtin_amdgcn_mfma_f32_16x16x32_bf16(a1, bfr[1][1], c1, 0, 0, 0);
#pragma unroll
      for (int rr = 0; rr < 4; rr++) {
        fa0 += __builtin_amdgcn_exp2f(c0[rr] * KS_);
        fa1 += __builtin_amdgcn_exp2f(c1[rr] * KS_);
      }
    }
    fa0 += __shfl_xor(fa0, 16); fa0 += __shfl_xor(fa0, 32);
    fa1 += __shfl_xor(fa1, 16); fa1 += __shfl_xor(fa1, 32);
    if (lane < 16) {
      rdg[(size_t)(bh * 8 + m) * 2048 + rt0 * 16 + lane] = -__builtin_amdgcn_logf(fa0);
      rdg[(size_t)(bh * 8 + m) * 2048 + (rt0 + 1) * 16 + lane] = -__builtin_amdgcn_logf(fa1);
    }
  }
}

// ---------- attention pass 2: loads at point of use (TLP over ILP); grid (z 8, itp 8, bh 16) ----------
__global__ __launch_bounds__(256) void k_attn_out6(const short* __restrict__ qfrag, const short* __restrict__ kfrag,
                                                   const short* __restrict__ vfrag, const float* __restrict__ rdg,
                                                   short* __restrict__ ao) {
  __shared__ float red[4 * 64 * 17];
  int z = blockIdx.x, itp = blockIdx.y, bh = blockIdx.z;
  int b = bh >> 3, h = bh & 7;
  int t = threadIdx.x, w = t >> 6, lane = t & 63, quad = lane >> 4, l16 = lane & 15;
  const float* rb = rdg + (size_t)bh * 16384;
  f32x4 z4 = {0, 0, 0, 0};
  bf16x8 qf[2][2][2];
#pragma unroll
  for (int iti = 0; iti < 2; iti++)
#pragma unroll
    for (int mm = 0; mm < 2; mm++)
#pragma unroll
      for (int ks = 0; ks < 2; ks++)
        qf[iti][mm][ks] = *(const bf16x8*)(qfrag +
            ((size_t)((bh * 128 + (2 * w + mm) * 16 + itp * 2 + iti) * 2 + ks)) * 512 + lane * 8);
  f32x4 acc[2][4];
#pragma unroll
  for (int iti = 0; iti < 2; iti++)
#pragma unroll
    for (int dt = 0; dt < 4; dt++) acc[iti][dt] = z4;
#pragma unroll 1
  for (int jc = 0; jc < 8; jc++) {
    bf16x8 vf[4][2], kf[2][2];
    float4 nv0[2], nv1[2];
#pragma unroll
    for (int dt = 0; dt < 4; dt++)
#pragma unroll
      for (int jf = 0; jf < 2; jf++)
        vf[dt][jf] = *(const bf16x8*)(vfrag + ((((size_t)(bh * 8 + jc) * 4 + w) * 4 + dt) * 2 + jf) * 512 + lane * 8);
#pragma unroll
    for (int jf = 0; jf < 2; jf++) {
      const short* kp = kfrag + ((size_t)((bh * 128 + z * 16 + jc * 2 + jf) * 2)) * 512 + lane * 8;
      kf[jf][0] = *(const bf16x8*)kp;
      kf[jf][1] = *(const bf16x8*)(kp + 512);
      nv0[jf] = *(const float4*)(rb + (size_t)(2 * w) * 2048 + z * 256 + jc * 32 + jf * 16 + quad * 4);
      nv1[jf] = *(const float4*)(rb + (size_t)(2 * w + 1) * 2048 + z * 256 + jc * 32 + jf * 16 + quad * 4);
    }
    float n0[2][4] = {{nv0[0].x, nv0[0].y, nv0[0].z, nv0[0].w}, {nv0[1].x, nv0[1].y, nv0[1].z, nv0[1].w}};
    float n1[2][4] = {{nv1[0].x, nv1[0].y, nv1[0].z, nv1[0].w}, {nv1[1].x, nv1[1].y, nv1[1].z, nv1[1].w}};
#pragma unroll
    for (int iti = 0; iti < 2; iti++) {
      f32x4 c[2][2] = {{z4, z4}, {z4, z4}};
#pragma unroll
      for (int jf = 0; jf < 2; jf++)
#pragma unroll
        for (int mm = 0; mm < 2; mm++) {
          c[jf][mm] = __builtin_amdgcn_mfma_f32_16x16x32_bf16(kf[jf][0], qf[iti][mm][0], c[jf][mm], 0, 0, 0);
          c[jf][mm] = __builtin_amdgcn_mfma_f32_16x16x32_bf16(kf[jf][1], qf[iti][mm][1], c[jf][mm], 0, 0, 0);
        }
      bf16x8 pf[2];
#pragma unroll
      for (int jf = 0; jf < 2; jf++) {
        unsigned u[8];
#pragma unroll
        for (int e = 0; e < 4; e++) {
          u[e]     = __builtin_bit_cast(unsigned, __builtin_amdgcn_exp2f(fmaf(c[jf][0][e], KS_, n0[jf][e]))) + 0x8000u;
          u[e + 4] = __builtin_bit_cast(unsigned, __builtin_amdgcn_exp2f(fmaf(c[jf][1][e], KS_, n1[jf][e]))) + 0x8000u;
        }
        uint4 pv;
        pv.x = __builtin_amdgcn_perm(u[1], u[0], 0x07060302u);
        pv.y = __builtin_amdgcn_perm(u[3], u[2], 0x07060302u);
        pv.z = __builtin_amdgcn_perm(u[5], u[4], 0x07060302u);
        pv.w = __builtin_amdgcn_perm(u[7], u[6], 0x07060302u);
        pf[jf] = __builtin_bit_cast(bf16x8, pv);
      }
#pragma unroll
      for (int dt = 0; dt < 4; dt++)
#pragma unroll
        for (int jf = 0; jf < 2; jf++)
          acc[iti][dt] = __builtin_amdgcn_mfma_f32_16x16x32_bf16(vf[dt][jf], pf[jf], acc[iti][dt], 0, 0, 0);
    }
  }
  for (int iti = 0; iti < 2; iti++) {
#pragma unroll
    for (int dt = 0; dt < 4; dt++)
#pragma unroll
      for (int rr = 0; rr < 4; rr++)
        red[w * 1088 + (dt * 16 + quad * 4 + rr) * 17 + l16] = acc[iti][dt][rr];
    __syncthreads();
    {
      int i = t >> 4, dg = t & 15;
      float s[4] = {0, 0, 0, 0};
#pragma unroll
      for (int w2 = 0; w2 < 4; w2++)
#pragma unroll
        for (int r2 = 0; r2 < 4; r2++)
          s[r2] += red[w2 * 1088 + (dg * 4 + r2) * 17 + i];
      bf16x4 ov;
#pragma unroll
      for (int r2 = 0; r2 < 4; r2++) ov[r2] = f2bf(s[r2]);
      *(bf16x4*)(ao + (size_t)((b * 256 + itp * 32 + iti * 16 + i) * 8 + z) * 512 + h * 64 + dg * 4) = ov;
    }
    __syncthreads();
  }
}

// ---------- fused residual(np split-K partials) + layernorm; optional bf16 copy ----------
__global__ __launch_bounds__(256) void k_ln(const float* __restrict__ X, const float* __restrict__ P, int np,
                                            const float* __restrict__ g, const float* __restrict__ be,
                                            float* __restrict__ Y, short* __restrict__ Ybf) {
  __shared__ float sm[8];
  int row = blockIdx.x, t = threadIdx.x;
  int lane = t & 63, w = t >> 6;
  size_t base = (size_t)row * 256;
  float v = X[base + t];
  for (int p = 0; p < np; p++) v += P[(size_t)p * 1048576 + base + t];
  float s = v;
  s += __shfl_xor(s, 1); s += __shfl_xor(s, 2); s += __shfl_xor(s, 4);
  s += __shfl_xor(s, 8); s += __shfl_xor(s, 16); s += __shfl_xor(s, 32);
  if (lane == 0) sm[w] = s;
  __syncthreads();
  float mu = (sm[0] + sm[1] + sm[2] + sm[3]) * (1.0f / 256.0f);
  float dv = v - mu;
  float s2 = dv * dv;
  s2 += __shfl_xor(s2, 1); s2 += __shfl_xor(s2, 2); s2 += __shfl_xor(s2, 4);
  s2 += __shfl_xor(s2, 8); s2 += __shfl_xor(s2, 16); s2 += __shfl_xor(s2, 32);
  if (lane == 0) sm[4 + w] = s2;
  __syncthreads();
  float var = (sm[4] + sm[5] + sm[6] + sm[7]) * (1.0f / 256.0f);
  float rs = rsqrtf(var + 1e-5f);
  float res = dv * rs * g[t] + be[t];
  Y[base + t] = res;
  if (Ybf) Ybf[base + t] = f2bf(res);
}

extern "C" void kernel_launch(void* const* d_in, const int* in_sizes, int n_in,
                              void* d_out, int out_size, void* d_ws, size_t ws_size,
                              hipStream_t stream) {
  const float* x    = (const float*)d_in[0];
  const float* Wq   = (const float*)d_in[1];
  const float* Wkv  = (const float*)d_in[2];
  const float* Wout = (const float*)d_in[3];
  const float* bout = (const float*)d_in[4];
  const float* g1   = (const float*)d_in[5];
  const float* be1  = (const float*)d_in[6];
  const float* Wff1 = (const float*)d_in[7];
  const float* bff1 = (const float*)d_in[8];
  const float* Wff2 = (const float*)d_in[9];
  const float* bff2 = (const float*)d_in[10];
  const float* g2   = (const float*)d_in[11];
  const float* be2  = (const float*)d_in[12];
  float* out = (float*)d_out;
  float* w = (float*)d_ws;

  // fp32 zone
  float* xt   = w;              // 1,048,576
  float* part = w + 1048576;    // split-K partials (4 x 1M, two phases)
  float* y    = w + 9437184;    // 1,048,576
  float* rdg  = w + 11534336;   //   262,144  -log2(den), [bh*8+m][2048]
  // bf16 zone
  short* sb     = (short*)(w + 11796480);
  short* qfrag  = sb;                    // 2,097,152
  short* kfrag  = sb + 2097152;          // 2,097,152
  short* vfrag  = sb + 4194304;          // 2,097,152
  short* xt_bf  = sb + 6291456;          // 1,048,576
  short* ao_bf  = sb + 7340032;          // 2,097,152
  short* y_bf   = sb + 9437184;          // 1,048,576
  short* gg_bf  = sb + 10485760;         // 4,194,304
  short* WqkvT  = sb + 14680064;         //   393,216  [1536][256]
  short* WoutT  = sb + 15073280;         // 8,388,608
  short* Wff1T  = sb + 23461888;         //   524,288
  short* Wff2T  = sb + 23986176;         //   262,144

  k_prep_all<<<10368, 256, 0, stream>>>(x, xt, xt_bf, Wq, Wkv, Wout, Wff1, Wff2,
                                        WqkvT, WoutT, Wff1T, Wff2T);
  k_gemm_qkv<<<dim3(24, 64), 256, 0, stream>>>(xt_bf, WqkvT, qfrag, kfrag, vfrag);
  k_attn_den5<<<dim3(16, 4, 16), 256, 0, stream>>>(qfrag, kfrag, rdg);
  k_attn_out6<<<dim3(8, 8, 16), 256, 0, stream>>>(qfrag, kfrag, vfrag, rdg, ao_bf);
  k_gemm_bf<<<dim3(32, 8, 4), 256, 0, stream>>>(ao_bf, WoutT, bout, part, 512, 2048, 4096, 1024);
  k_ln<<<4096, 256, 0, stream>>>(xt, part, 4, g1, be1, y, y_bf);
  k_ff1g<<<dim3(16, 64), 256, 0, stream>>>(y_bf, Wff1T, bff1, gg_bf);
  k_gemm_bf<<<dim3(4, 64, 4), 256, 0, stream>>>(gg_bf, Wff2T, bff2, part, 4096, 256, 1024, 256);
  k_ln<<<4096, 256, 0, stream>>>(y, part, 4, g2, be2, out, nullptr);
}

// Round 8
// 214.776 us; speedup vs baseline: 1.0744x; 1.0025x over previous
//
#include <hip/hip_runtime.h>
#include <math.h>

#define KS_ 0.1803368801111244f   // 0.125 * log2(e)

typedef __attribute__((ext_vector_type(8))) short bf16x8;
typedef __attribute__((ext_vector_type(4))) short bf16x4;
typedef __attribute__((ext_vector_type(4))) float f32x4;

__device__ inline short f2bf(float f) {
  unsigned u = __builtin_bit_cast(unsigned, f);
  u += 0x7fff + ((u >> 16) & 1);
  return (short)(u >> 16);
}

// async global->LDS 16B DMA (dest = wave-uniform base + lane*16)
__device__ inline void gload16(const short* g, short* l) {
  __builtin_amdgcn_global_load_lds(
      (const __attribute__((address_space(1))) void*)g,
      (__attribute__((address_space(3))) void*)l, 16, 0, 0);
}

// ---------- helper: 32x32 transpose tile of W [K][N] -> WT bf16 [N][K] ----------
__device__ inline void wt_tile(const float* __restrict__ W, short* __restrict__ WT,
                               int K, int N, int bx, int by, int t, float (*tile)[33]) {
  int n0 = bx * 32, k0 = by * 32;
  int tx = t & 31, ty = t >> 5;
#pragma unroll
  for (int r = 0; r < 32; r += 8)
    tile[ty + r][tx] = W[(size_t)(k0 + ty + r) * N + n0 + tx];
  __syncthreads();
#pragma unroll
  for (int r = 0; r < 32; r += 8)
    WT[(size_t)(n0 + ty + r) * K + k0 + tx] = f2bf(tile[tx][ty + r]);
}

// ---------- mega prep: x-transpose + all 5 weight transposes in one launch ----------
__global__ __launch_bounds__(256) void k_prep_all(const float* __restrict__ x, float* __restrict__ xt,
                                                  short* __restrict__ xtbf,
                                                  const float* __restrict__ Wq, const float* __restrict__ Wkv,
                                                  const float* __restrict__ Wout, const float* __restrict__ Wff1,
                                                  const float* __restrict__ Wff2,
                                                  short* __restrict__ WqkvT, short* __restrict__ WoutT,
                                                  short* __restrict__ Wff1T, short* __restrict__ Wff2T) {
  __shared__ float tile[32][33];
  int bid = blockIdx.x, t = threadIdx.x;
  if (bid < 8192) {
    wt_tile(Wout, WoutT, 4096, 2048, bid & 63, bid >> 6, t, tile);
  } else if (bid < 9216) {
    int r = bid - 8192;
    int bx = r & 7, by = (r >> 3) & 7, bm = r >> 6;
    int b = bm >> 3, m = bm & 7;
    int d0 = bx * 32, n0 = by * 32;
    int tx = t & 31, ty = t >> 5;
#pragma unroll
    for (int rr = 0; rr < 32; rr += 8) {
      int d = d0 + ty + rr, n = n0 + tx;
      tile[ty + rr][tx] = x[((size_t)(b * 256 + d) * 8 + m) * 256 + n];
    }
    __syncthreads();
#pragma unroll
    for (int rr = 0; rr < 32; rr += 8) {
      int n = n0 + ty + rr, d = d0 + tx;
      float v = tile[tx][ty + rr];
      size_t idx = ((size_t)(b * 256 + n) * 8 + m) * 256 + d;
      xt[idx] = v;
      xtbf[idx] = f2bf(v);
    }
  } else if (bid < 9344) {
    int r = bid - 9216;
    wt_tile(Wq, WqkvT, 256, 512, r & 15, r >> 4, t, tile);
  } else if (bid < 9600) {
    int r = bid - 9344;
    wt_tile(Wkv, WqkvT + 131072, 256, 1024, r & 31, r >> 5, t, tile);
  } else if (bid < 10112) {
    int r = bid - 9600;
    wt_tile(Wff1, Wff1T, 256, 2048, r & 63, r >> 6, t, tile);
  } else {
    int r = bid - 10112;
    wt_tile(Wff2, Wff2T, 1024, 256, r & 7, r >> 3, t, tile);
  }
}

// ---------- fused qkv GEMM with fragment-layout epilogue ----------
// A = xt_bf [4096][256]; Bt = WqkvT [1536][256]. grid (24, 64).
__global__ __launch_bounds__(256) void k_gemm_qkv(const short* __restrict__ A, const short* __restrict__ Bt,
                                                  short* __restrict__ qfrag, short* __restrict__ kfrag,
                                                  short* __restrict__ vfrag) {
  __shared__ short As[2][2048];
  __shared__ short Bs[2][2048];
  __shared__ short Cs[64 * 72];
  int t = threadIdx.x;
  int bx = blockIdx.x, by = blockIdx.y;
  int sel = bx >> 3, h = bx & 7;
  int row0 = by * 64, col0 = bx * 64;
  int b = by >> 5, n0 = (by * 8) & 255;
  int bh = b * 8 + h;
  int w = t >> 6, lane = t & 63, quad = lane >> 4, l16 = lane & 15;
  int wr = w >> 1, wc = w & 1;
  int r = t >> 2;
  int cs = ((t & 3) ^ ((r >> 1) & 3)) * 8;
  const short* Ag = A + (size_t)(row0 + r) * 256 + cs;
  const short* Bg = Bt + (size_t)(col0 + r) * 256 + cs;
  int sw = (l16 >> 1) & 3;
  int chk = (quad ^ sw) * 8;
  int aoff[2], boff[2];
#pragma unroll
  for (int rf = 0; rf < 2; rf++) {
    aoff[rf] = (wr * 32 + rf * 16 + l16) * 32 + chk;
    boff[rf] = (wc * 32 + rf * 16 + l16) * 32 + chk;
  }
  f32x4 acc[2][2] = {{{0,0,0,0},{0,0,0,0}},{{0,0,0,0},{0,0,0,0}}};
  gload16(Ag, &As[0][w * 512]);
  gload16(Bg, &Bs[0][w * 512]);
  __syncthreads();
  int buf = 0;
  for (int k0 = 0; k0 < 256; k0 += 32) {
    int nb = buf ^ 1;
    if (k0 + 32 < 256) {
      gload16(Ag + k0 + 32, &As[nb][w * 512]);
      gload16(Bg + k0 + 32, &Bs[nb][w * 512]);
    }
    bf16x8 af[2], bf[2];
#pragma unroll
    for (int rf = 0; rf < 2; rf++) af[rf] = *(const bf16x8*)&As[buf][aoff[rf]];
#pragma unroll
    for (int cf = 0; cf < 2; cf++) bf[cf] = *(const bf16x8*)&Bs[buf][boff[cf]];
#pragma unroll
    for (int rf = 0; rf < 2; rf++)
#pragma unroll
      for (int cf = 0; cf < 2; cf++)
        acc[rf][cf] = __builtin_amdgcn_mfma_f32_16x16x32_bf16(af[rf], bf[cf], acc[rf][cf], 0, 0, 0);
    __syncthreads();
    buf = nb;
  }
  // ---- stage result tile to LDS as bf16 ----
  if (sel < 2) {
#pragma unroll
    for (int rf = 0; rf < 2; rf++)
#pragma unroll
      for (int cf = 0; cf < 2; cf++) {
        int col = wc * 32 + cf * 16 + l16;
#pragma unroll
        for (int rr = 0; rr < 4; rr++)
          Cs[(wr * 32 + rf * 16 + quad * 4 + rr) * 72 + col] = f2bf(acc[rf][cf][rr]);
      }
  } else {
#pragma unroll
    for (int rf = 0; rf < 2; rf++)
#pragma unroll
      for (int cf = 0; cf < 2; cf++) {
        int col = wc * 32 + cf * 16 + l16;
        bf16x4 pk;
#pragma unroll
        for (int rr = 0; rr < 4; rr++) pk[rr] = f2bf(acc[rf][cf][rr]);
        *(bf16x4*)&Cs[col * 72 + wr * 32 + rf * 16 + quad * 4] = pk;
      }
  }
  __syncthreads();
  // ---- fragment-order global writes ----
  if (sel < 2) {
    short* dst = sel ? kfrag : qfrag;
    int it = n0 >> 4, l16b = n0 & 8;
#pragma unroll
    for (int cidx = 0; cidx < 2; cidx++) {
      int chunk = t + cidx * 256;        // bits: m[8:6] ks[5] q2[4:3] n[2:0]
      int m = chunk >> 6, ks2 = (chunk >> 5) & 1, q2 = (chunk >> 3) & 3, n = chunk & 7;
      bf16x8 val = *(const bf16x8*)&Cs[(n * 8 + m) * 72 + ks2 * 32 + q2 * 8];
      size_t off = ((size_t)(bh * 128 + m * 16 + it) * 2 + ks2) * 512 + (q2 * 16 + l16b + n) * 8;
      *(bf16x8*)(dst + off) = val;
    }
  } else {
    int jc = n0 >> 5, jf = (n0 >> 4) & 1, qbase = (n0 & 8) >> 2;   // quad base 0 or 2
#pragma unroll
    for (int cidx = 0; cidx < 2; cidx++) {
      int chunk = t + cidx * 256;        // bits: qd[8] m0[7:6] dt[5:4] l16[3:0]
      int qd = chunk >> 8, m0 = (chunk >> 6) & 3, dtt = (chunk >> 4) & 3, l16c = chunk & 15;
      int d = dtt * 16 + l16c;
      unsigned u[4];
#pragma unroll
      for (int e3 = 0; e3 < 4; e3++)
        u[e3] = *(const unsigned*)&Cs[d * 72 + qd * 32 + e3 * 8 + 2 * m0];
      uint4 pv;
      pv.x = __builtin_amdgcn_perm(u[1], u[0], 0x05040100u);
      pv.y = __builtin_amdgcn_perm(u[3], u[2], 0x05040100u);
      pv.z = __builtin_amdgcn_perm(u[1], u[0], 0x07060302u);
      pv.w = __builtin_amdgcn_perm(u[3], u[2], 0x07060302u);
      int quad2 = qbase + qd;
      size_t cid = (((size_t)(bh * 8 + jc) * 4 + m0) * 4 + dtt) * 2 + jf;
      *(bf16x8*)(vfrag + cid * 512 + (quad2 * 16 + l16c) * 8) = __builtin_bit_cast(bf16x8, pv);
    }
  }
}

// ---------- bf16 MFMA GEMM with split-K; global_load_lds double-buffered main loop ----------
__global__ __launch_bounds__(256) void k_gemm_bf(const short* __restrict__ A, const short* __restrict__ Bt,
                                                 const float* __restrict__ bias, float* __restrict__ C,
                                                 int M, int N, int K, int Ks) {
  __shared__ short As[2][2048];
  __shared__ short Bs[2][2048];
  int t = threadIdx.x;
  int row0 = blockIdx.y * 64, col0 = blockIdx.x * 64;
  int kp = blockIdx.z;
  int kbeg = kp * Ks, kend = kbeg + Ks;
  int w = t >> 6, lane = t & 63, quad = lane >> 4, l16 = lane & 15;
  int wr = w >> 1, wc = w & 1;
  int r = t >> 2;
  int cs = ((t & 3) ^ ((r >> 1) & 3)) * 8;
  const short* Ag = A + (size_t)(row0 + r) * K + cs;
  const short* Bg = Bt + (size_t)(col0 + r) * K + cs;
  int sw = (l16 >> 1) & 3;
  int chk = (quad ^ sw) * 8;
  int aoff[2], boff[2];
#pragma unroll
  for (int rf = 0; rf < 2; rf++) {
    aoff[rf] = (wr * 32 + rf * 16 + l16) * 32 + chk;
    boff[rf] = (wc * 32 + rf * 16 + l16) * 32 + chk;
  }
  f32x4 acc[2][2] = {{{0,0,0,0},{0,0,0,0}},{{0,0,0,0},{0,0,0,0}}};
  gload16(Ag + kbeg, &As[0][w * 512]);
  gload16(Bg + kbeg, &Bs[0][w * 512]);
  __syncthreads();
  int buf = 0;
  for (int k0 = kbeg; k0 < kend; k0 += 32) {
    int nb = buf ^ 1;
    if (k0 + 32 < kend) {
      gload16(Ag + k0 + 32, &As[nb][w * 512]);
      gload16(Bg + k0 + 32, &Bs[nb][w * 512]);
    }
    bf16x8 af[2], bf[2];
#pragma unroll
    for (int rf = 0; rf < 2; rf++) af[rf] = *(const bf16x8*)&As[buf][aoff[rf]];
#pragma unroll
    for (int cf = 0; cf < 2; cf++) bf[cf] = *(const bf16x8*)&Bs[buf][boff[cf]];
#pragma unroll
    for (int rf = 0; rf < 2; rf++)
#pragma unroll
      for (int cf = 0; cf < 2; cf++)
        acc[rf][cf] = __builtin_amdgcn_mfma_f32_16x16x32_bf16(af[rf], bf[cf], acc[rf][cf], 0, 0, 0);
    __syncthreads();
    buf = nb;
  }
  float* Cp = C + (size_t)kp * M * N;
#pragma unroll
  for (int rf = 0; rf < 2; rf++)
#pragma unroll
    for (int cf = 0; cf < 2; cf++) {
      int col = col0 + wc * 32 + cf * 16 + l16;
      float vb = (bias && kp == 0) ? bias[col] : 0.0f;
#pragma unroll
      for (int rr = 0; rr < 4; rr++) {
        int row = row0 + wr * 32 + rf * 16 + quad * 4 + rr;
        Cp[(size_t)row * N + col] = acc[rf][cf][rr] + vb;
      }
    }
}

// ---------- fused ff1 GEMM + GEGLU ----------
__global__ __launch_bounds__(256) void k_ff1g(const short* __restrict__ A, const short* __restrict__ Bt,
                                              const float* __restrict__ bias, short* __restrict__ gg) {
  __shared__ short As[2][2048];
  __shared__ short Ba[2][2048];
  __shared__ short Bgs[2][2048];
  int t = threadIdx.x;
  int colA0 = blockIdx.x * 64, row0 = blockIdx.y * 64;
  int w = t >> 6, lane = t & 63, quad = lane >> 4, l16 = lane & 15;
  int wr = w >> 1, wc = w & 1;
  int r = t >> 2;
  int cs = ((t & 3) ^ ((r >> 1) & 3)) * 8;
  const short* Ag  = A + (size_t)(row0 + r) * 256 + cs;
  const short* Bpa = Bt + (size_t)(colA0 + r) * 256 + cs;
  const short* Bpg = Bt + (size_t)(1024 + colA0 + r) * 256 + cs;
  int sw = (l16 >> 1) & 3;
  int chk = (quad ^ sw) * 8;
  int aoff[2], boff[2];
#pragma unroll
  for (int rf = 0; rf < 2; rf++) {
    aoff[rf] = (wr * 32 + rf * 16 + l16) * 32 + chk;
    boff[rf] = (wc * 32 + rf * 16 + l16) * 32 + chk;
  }
  f32x4 za = {0, 0, 0, 0};
  f32x4 acc_a[2][2] = {{za, za}, {za, za}};
  f32x4 acc_g[2][2] = {{za, za}, {za, za}};
  gload16(Ag, &As[0][w * 512]);
  gload16(Bpa, &Ba[0][w * 512]);
  gload16(Bpg, &Bgs[0][w * 512]);
  __syncthreads();
  int buf = 0;
  for (int k0 = 0; k0 < 256; k0 += 32) {
    int nb = buf ^ 1;
    if (k0 + 32 < 256) {
      gload16(Ag + k0 + 32, &As[nb][w * 512]);
      gload16(Bpa + k0 + 32, &Ba[nb][w * 512]);
      gload16(Bpg + k0 + 32, &Bgs[nb][w * 512]);
    }
    bf16x8 af[2], ba[2], bg[2];
#pragma unroll
    for (int rf = 0; rf < 2; rf++) af[rf] = *(const bf16x8*)&As[buf][aoff[rf]];
#pragma unroll
    for (int cf = 0; cf < 2; cf++) {
      ba[cf] = *(const bf16x8*)&Ba[buf][boff[cf]];
      bg[cf] = *(const bf16x8*)&Bgs[buf][boff[cf]];
    }
#pragma unroll
    for (int rf = 0; rf < 2; rf++)
#pragma unroll
      for (int cf = 0; cf < 2; cf++) {
        acc_a[rf][cf] = __builtin_amdgcn_mfma_f32_16x16x32_bf16(af[rf], ba[cf], acc_a[rf][cf], 0, 0, 0);
        acc_g[rf][cf] = __builtin_amdgcn_mfma_f32_16x16x32_bf16(af[rf], bg[cf], acc_g[rf][cf], 0, 0, 0);
      }
    __syncthreads();
    buf = nb;
  }
#pragma unroll
  for (int rf = 0; rf < 2; rf++)
#pragma unroll
    for (int cf = 0; cf < 2; cf++) {
      int col = colA0 + wc * 32 + cf * 16 + l16;
      float ba_ = bias[col], bg_ = bias[1024 + col];
#pragma unroll
      for (int rr = 0; rr < 4; rr++) {
        int row = row0 + wr * 32 + rf * 16 + quad * 4 + rr;
        float a = acc_a[rf][cf][rr] + ba_;
        float g = acc_g[rf][cf][rr] + bg_;
        float ge = 0.5f * g * (1.0f + erff(g * 0.70710678118654752f));
        gg[(size_t)row * 1024 + col] = f2bf(a * ge);
      }
    }
}

// ---------- attention pass 1: XCD-swizzled flat grid 1024 ----------
// bid -> xcd=bid&7, j=bid>>3; bh = xcd*2 + (j>>6); idx=j&63 -> ct2 = idx&15, mp = idx>>4.
// Groups all 64 blocks sharing one bh onto a single XCD (per-XCD L2 working set ~1.7 MB).
__global__ __launch_bounds__(256) void k_attn_den5(const short* __restrict__ qfrag, const short* __restrict__ kfrag,
                                                   float* __restrict__ rdg) {
  int bid = blockIdx.x;
  int j = bid >> 3;
  int bh = ((bid & 7) << 1) + (j >> 6);
  int idx = j & 63;
  int ct2 = idx & 15, mp = idx >> 4;
  int t = threadIdx.x;
  int w = t >> 6, lane = t & 63;
  int rt0 = ct2 * 8 + w * 2;
  bf16x8 bfr[2][2];
#pragma unroll
  for (int cf = 0; cf < 2; cf++)
#pragma unroll
    for (int ks = 0; ks < 2; ks++)
      bfr[cf][ks] = *(const bf16x8*)(kfrag + ((size_t)((bh * 128 + rt0 + cf) * 2 + ks)) * 512 + lane * 8);
  for (int mi = 0; mi < 2; mi++) {
    int m = mp * 2 + mi;
    float fa0 = 0.0f, fa1 = 0.0f;
#pragma unroll 4
    for (int it2 = 0; it2 < 16; it2++) {
      const short* ap = qfrag + ((size_t)((bh * 128 + m * 16 + it2) * 2)) * 512 + lane * 8;
      bf16x8 a0 = *(const bf16x8*)ap;
      bf16x8 a1 = *(const bf16x8*)(ap + 512);
      f32x4 c0 = {0, 0, 0, 0}, c1 = {0, 0, 0, 0};
      c0 = __builtin_amdgcn_mfma_f32_16x16x32_bf16(a0, bfr[0][0], c0, 0, 0, 0);
      c0 = __builtin_amdgcn_mfma_f32_16x16x32_bf16(a1, bfr[0][1], c0, 0, 0, 0);
      c1 = __builtin_amdgcn_mfma_f32_16x16x32_bf16(a0, bfr[1][0], c1, 0, 0, 0);
      c1 = __builtin_amdgcn_mfma_f32_16x16x32_bf16(a1, bfr[1][1], c1, 0, 0, 0);
#pragma unroll
      for (int rr = 0; rr < 4; rr++) {
        fa0 += __builtin_amdgcn_exp2f(c0[rr] * KS_);
        fa1 += __builtin_amdgcn_exp2f(c1[rr] * KS_);
      }
    }
    fa0 += __shfl_xor(fa0, 16); fa0 += __shfl_xor(fa0, 32);
    fa1 += __shfl_xor(fa1, 16); fa1 += __shfl_xor(fa1, 32);
    if (lane < 16) {
      rdg[(size_t)(bh * 8 + m) * 2048 + rt0 * 16 + lane] = -__builtin_amdgcn_logf(fa0);
      rdg[(size_t)(bh * 8 + m) * 2048 + (rt0 + 1) * 16 + lane] = -__builtin_amdgcn_logf(fa1);
    }
  }
}

// ---------- attention pass 2: XCD-swizzled flat grid 1024; loads at point of use ----------
// bid -> xcd=bid&7, j=bid>>3; bh = xcd*2 + (j>>6); idx=j&63 -> z = idx&7, itp = idx>>3.
__global__ __launch_bounds__(256) void k_attn_out6(const short* __restrict__ qfrag, const short* __restrict__ kfrag,
                                                   const short* __restrict__ vfrag, const float* __restrict__ rdg,
                                                   short* __restrict__ ao) {
  __shared__ float red[4 * 64 * 17];
  int bid = blockIdx.x;
  int j = bid >> 3;
  int bh = ((bid & 7) << 1) + (j >> 6);
  int idx = j & 63;
  int z = idx & 7, itp = idx >> 3;
  int b = bh >> 3, h = bh & 7;
  int t = threadIdx.x, w = t >> 6, lane = t & 63, quad = lane >> 4, l16 = lane & 15;
  const float* rb = rdg + (size_t)bh * 16384;
  f32x4 z4 = {0, 0, 0, 0};
  bf16x8 qf[2][2][2];
#pragma unroll
  for (int iti = 0; iti < 2; iti++)
#pragma unroll
    for (int mm = 0; mm < 2; mm++)
#pragma unroll
      for (int ks = 0; ks < 2; ks++)
        qf[iti][mm][ks] = *(const bf16x8*)(qfrag +
            ((size_t)((bh * 128 + (2 * w + mm) * 16 + itp * 2 + iti) * 2 + ks)) * 512 + lane * 8);
  f32x4 acc[2][4];
#pragma unroll
  for (int iti = 0; iti < 2; iti++)
#pragma unroll
    for (int dt = 0; dt < 4; dt++) acc[iti][dt] = z4;
#pragma unroll 1
  for (int jc = 0; jc < 8; jc++) {
    bf16x8 vf[4][2], kf[2][2];
    float4 nv0[2], nv1[2];
#pragma unroll
    for (int dt = 0; dt < 4; dt++)
#pragma unroll
      for (int jf = 0; jf < 2; jf++)
        vf[dt][jf] = *(const bf16x8*)(vfrag + ((((size_t)(bh * 8 + jc) * 4 + w) * 4 + dt) * 2 + jf) * 512 + lane * 8);
#pragma unroll
    for (int jf = 0; jf < 2; jf++) {
      const short* kp = kfrag + ((size_t)((bh * 128 + z * 16 + jc * 2 + jf) * 2)) * 512 + lane * 8;
      kf[jf][0] = *(const bf16x8*)kp;
      kf[jf][1] = *(const bf16x8*)(kp + 512);
      nv0[jf] = *(const float4*)(rb + (size_t)(2 * w) * 2048 + z * 256 + jc * 32 + jf * 16 + quad * 4);
      nv1[jf] = *(const float4*)(rb + (size_t)(2 * w + 1) * 2048 + z * 256 + jc * 32 + jf * 16 + quad * 4);
    }
    float n0[2][4] = {{nv0[0].x, nv0[0].y, nv0[0].z, nv0[0].w}, {nv0[1].x, nv0[1].y, nv0[1].z, nv0[1].w}};
    float n1[2][4] = {{nv1[0].x, nv1[0].y, nv1[0].z, nv1[0].w}, {nv1[1].x, nv1[1].y, nv1[1].z, nv1[1].w}};
#pragma unroll
    for (int iti = 0; iti < 2; iti++) {
      f32x4 c[2][2] = {{z4, z4}, {z4, z4}};
#pragma unroll
      for (int jf = 0; jf < 2; jf++)
#pragma unroll
        for (int mm = 0; mm < 2; mm++) {
          c[jf][mm] = __builtin_amdgcn_mfma_f32_16x16x32_bf16(kf[jf][0], qf[iti][mm][0], c[jf][mm], 0, 0, 0);
          c[jf][mm] = __builtin_amdgcn_mfma_f32_16x16x32_bf16(kf[jf][1], qf[iti][mm][1], c[jf][mm], 0, 0, 0);
        }
      bf16x8 pf[2];
#pragma unroll
      for (int jf = 0; jf < 2; jf++) {
        unsigned u[8];
#pragma unroll
        for (int e = 0; e < 4; e++) {
          u[e]     = __builtin_bit_cast(unsigned, __builtin_amdgcn_exp2f(fmaf(c[jf][0][e], KS_, n0[jf][e]))) + 0x8000u;
          u[e + 4] = __builtin_bit_cast(unsigned, __builtin_amdgcn_exp2f(fmaf(c[jf][1][e], KS_, n1[jf][e]))) + 0x8000u;
        }
        uint4 pv;
        pv.x = __builtin_amdgcn_perm(u[1], u[0], 0x07060302u);
        pv.y = __builtin_amdgcn_perm(u[3], u[2], 0x07060302u);
        pv.z = __builtin_amdgcn_perm(u[5], u[4], 0x07060302u);
        pv.w = __builtin_amdgcn_perm(u[7], u[6], 0x07060302u);
        pf[jf] = __builtin_bit_cast(bf16x8, pv);
      }
#pragma unroll
      for (int dt = 0; dt < 4; dt++)
#pragma unroll
        for (int jf = 0; jf < 2; jf++)
          acc[iti][dt] = __builtin_amdgcn_mfma_f32_16x16x32_bf16(vf[dt][jf], pf[jf], acc[iti][dt], 0, 0, 0);
    }
  }
  for (int iti = 0; iti < 2; iti++) {
#pragma unroll
    for (int dt = 0; dt < 4; dt++)
#pragma unroll
      for (int rr = 0; rr < 4; rr++)
        red[w * 1088 + (dt * 16 + quad * 4 + rr) * 17 + l16] = acc[iti][dt][rr];
    __syncthreads();
    {
      int i = t >> 4, dg = t & 15;
      float s[4] = {0, 0, 0, 0};
#pragma unroll
      for (int w2 = 0; w2 < 4; w2++)
#pragma unroll
        for (int r2 = 0; r2 < 4; r2++)
          s[r2] += red[w2 * 1088 + (dg * 4 + r2) * 17 + i];
      bf16x4 ov;
#pragma unroll
      for (int r2 = 0; r2 < 4; r2++) ov[r2] = f2bf(s[r2]);
      *(bf16x4*)(ao + (size_t)((b * 256 + itp * 32 + iti * 16 + i) * 8 + z) * 512 + h * 64 + dg * 4) = ov;
    }
    __syncthreads();
  }
}

// ---------- fused residual(np split-K partials) + layernorm; optional bf16 copy ----------
__global__ __launch_bounds__(256) void k_ln(const float* __restrict__ X, const float* __restrict__ P, int np,
                                            const float* __restrict__ g, const float* __restrict__ be,
                                            float* __restrict__ Y, short* __restrict__ Ybf) {
  __shared__ float sm[8];
  int row = blockIdx.x, t = threadIdx.x;
  int lane = t & 63, w = t >> 6;
  size_t base = (size_t)row * 256;
  float v = X[base + t];
  for (int p = 0; p < np; p++) v += P[(size_t)p * 1048576 + base + t];
  float s = v;
  s += __shfl_xor(s, 1); s += __shfl_xor(s, 2); s += __shfl_xor(s, 4);
  s += __shfl_xor(s, 8); s += __shfl_xor(s, 16); s += __shfl_xor(s, 32);
  if (lane == 0) sm[w] = s;
  __syncthreads();
  float mu = (sm[0] + sm[1] + sm[2] + sm[3]) * (1.0f / 256.0f);
  float dv = v - mu;
  float s2 = dv * dv;
  s2 += __shfl_xor(s2, 1); s2 += __shfl_xor(s2, 2); s2 += __shfl_xor(s2, 4);
  s2 += __shfl_xor(s2, 8); s2 += __shfl_xor(s2, 16); s2 += __shfl_xor(s2, 32);
  if (lane == 0) sm[4 + w] = s2;
  __syncthreads();
  float var = (sm[4] + sm[5] + sm[6] + sm[7]) * (1.0f / 256.0f);
  float rs = rsqrtf(var + 1e-5f);
  float res = dv * rs * g[t] + be[t];
  Y[base + t] = res;
  if (Ybf) Ybf[base + t] = f2bf(res);
}

extern "C" void kernel_launch(void* const* d_in, const int* in_sizes, int n_in,
                              void* d_out, int out_size, void* d_ws, size_t ws_size,
                              hipStream_t stream) {
  const float* x    = (const float*)d_in[0];
  const float* Wq   = (const float*)d_in[1];
  const float* Wkv  = (const float*)d_in[2];
  const float* Wout = (const float*)d_in[3];
  const float* bout = (const float*)d_in[4];
  const float* g1   = (const float*)d_in[5];
  const float* be1  = (const float*)d_in[6];
  const float* Wff1 = (const float*)d_in[7];
  const float* bff1 = (const float*)d_in[8];
  const float* Wff2 = (const float*)d_in[9];
  const float* bff2 = (const float*)d_in[10];
  const float* g2   = (const float*)d_in[11];
  const float* be2  = (const float*)d_in[12];
  float* out = (float*)d_out;
  float* w = (float*)d_ws;

  // fp32 zone
  float* xt   = w;              // 1,048,576
  float* part = w + 1048576;    // split-K partials (4 x 1M, two phases)
  float* y    = w + 9437184;    // 1,048,576
  float* rdg  = w + 11534336;   //   262,144  -log2(den), [bh*8+m][2048]
  // bf16 zone
  short* sb     = (short*)(w + 11796480);
  short* qfrag  = sb;                    // 2,097,152
  short* kfrag  = sb + 2097152;          // 2,097,152
  short* vfrag  = sb + 4194304;          // 2,097,152
  short* xt_bf  = sb + 6291456;          // 1,048,576
  short* ao_bf  = sb + 7340032;          // 2,097,152
  short* y_bf   = sb + 9437184;          // 1,048,576
  short* gg_bf  = sb + 10485760;         // 4,194,304
  short* WqkvT  = sb + 14680064;         //   393,216  [1536][256]
  short* WoutT  = sb + 15073280;         // 8,388,608
  short* Wff1T  = sb + 23461888;         //   524,288
  short* Wff2T  = sb + 23986176;         //   262,144

  k_prep_all<<<10368, 256, 0, stream>>>(x, xt, xt_bf, Wq, Wkv, Wout, Wff1, Wff2,
                                        WqkvT, WoutT, Wff1T, Wff2T);
  k_gemm_qkv<<<dim3(24, 64), 256, 0, stream>>>(xt_bf, WqkvT, qfrag, kfrag, vfrag);
  k_attn_den5<<<1024, 256, 0, stream>>>(qfrag, kfrag, rdg);
  k_attn_out6<<<1024, 256, 0, stream>>>(qfrag, kfrag, vfrag, rdg, ao_bf);
  k_gemm_bf<<<dim3(32, 8, 4), 256, 0, stream>>>(ao_bf, WoutT, bout, part, 512, 2048, 4096, 1024);
  k_ln<<<4096, 256, 0, stream>>>(xt, part, 4, g1, be1, y, y_bf);
  k_ff1g<<<dim3(16, 64), 256, 0, stream>>>(y_bf, Wff1T, bff1, gg_bf);
  k_gemm_bf<<<dim3(4, 64, 4), 256, 0, stream>>>(gg_bf, Wff2T, bff2, part, 4096, 256, 1024, 256);
  k_ln<<<4096, 256, 0, stream>>>(y, part, 4, g2, be2, out, nullptr);
}

// Round 9
// 214.059 us; speedup vs baseline: 1.0780x; 1.0033x over previous
//
#include <hip/hip_runtime.h>
#include <math.h>

#define KS_ 0.1803368801111244f   // 0.125 * log2(e)

typedef __attribute__((ext_vector_type(8))) short bf16x8;
typedef __attribute__((ext_vector_type(4))) short bf16x4;
typedef __attribute__((ext_vector_type(4))) float f32x4;

__device__ inline short f2bf(float f) {
  unsigned u = __builtin_bit_cast(unsigned, f);
  u += 0x7fff + ((u >> 16) & 1);
  return (short)(u >> 16);
}

// async global->LDS 16B DMA (dest = wave-uniform base + lane*16)
__device__ inline void gload16(const short* g, short* l) {
  __builtin_amdgcn_global_load_lds(
      (const __attribute__((address_space(1))) void*)g,
      (__attribute__((address_space(3))) void*)l, 16, 0, 0);
}

// ---------- helper: 64x64 transpose tile of W [K][N] -> WT bf16 [N][K], bf16x4 stores ----------
// tile = 64*65 floats. load: 256B/wave coalesced; store: 8B/lane, 128B contiguous per 16 lanes.
__device__ inline void wt_tile64(const float* __restrict__ W, short* __restrict__ WT,
                                 int K, int N, int bx, int by, int t, float* tile) {
  int n0 = bx * 64, k0 = by * 64;
  int tx = t & 63, ty = t >> 6;
#pragma unroll
  for (int r = 0; r < 64; r += 4)
    tile[(size_t)(ty + r) * 65 + tx] = W[(size_t)(k0 + ty + r) * N + n0 + tx];
  __syncthreads();
  int kx = t & 15, ny = t >> 4;
#pragma unroll
  for (int rr = 0; rr < 64; rr += 16) {
    int n = n0 + ny + rr;
    bf16x4 pk;
#pragma unroll
    for (int e = 0; e < 4; e++) pk[e] = f2bf(tile[(size_t)(kx * 4 + e) * 65 + ny + rr]);
    *(bf16x4*)&WT[(size_t)n * K + k0 + kx * 4] = pk;
  }
}

// ---------- mega prep: x-transpose + all 5 weight transposes in one launch; grid 3360 ----------
__global__ __launch_bounds__(256) void k_prep_all(const float* __restrict__ x, float* __restrict__ xt,
                                                  short* __restrict__ xtbf,
                                                  const float* __restrict__ Wq, const float* __restrict__ Wkv,
                                                  const float* __restrict__ Wout, const float* __restrict__ Wff1,
                                                  const float* __restrict__ Wff2,
                                                  short* __restrict__ WqkvT, short* __restrict__ WoutT,
                                                  short* __restrict__ Wff1T, short* __restrict__ Wff2T) {
  __shared__ float tile[64 * 65];
  int bid = blockIdx.x, t = threadIdx.x;
  if (bid < 2048) {
    // Wout [4096][2048] -> WoutT [2048][4096]
    wt_tile64(Wout, WoutT, 4096, 2048, bid & 31, bid >> 5, t, tile);
  } else if (bid < 3072) {
    // x-transpose (unchanged 32x32 structure, re-indexed into flat tile)
    int r = bid - 2048;
    int bx = r & 7, by = (r >> 3) & 7, bm = r >> 6;
    int b = bm >> 3, m = bm & 7;
    int d0 = bx * 32, n0 = by * 32;
    int tx = t & 31, ty = t >> 5;
#pragma unroll
    for (int rr = 0; rr < 32; rr += 8) {
      int d = d0 + ty + rr, n = n0 + tx;
      tile[(size_t)(ty + rr) * 33 + tx] = x[((size_t)(b * 256 + d) * 8 + m) * 256 + n];
    }
    __syncthreads();
#pragma unroll
    for (int rr = 0; rr < 32; rr += 8) {
      int n = n0 + ty + rr, d = d0 + tx;
      float v = tile[(size_t)tx * 33 + ty + rr];
      size_t idx = ((size_t)(b * 256 + n) * 8 + m) * 256 + d;
      xt[idx] = v;
      xtbf[idx] = f2bf(v);
    }
  } else if (bid < 3104) {
    // Wq [256][512] -> WqkvT[0..] [512][256]
    int r = bid - 3072;
    wt_tile64(Wq, WqkvT, 256, 512, r & 7, r >> 3, t, tile);
  } else if (bid < 3168) {
    // Wkv [256][1024] -> WqkvT+131072 [1024][256]
    int r = bid - 3104;
    wt_tile64(Wkv, WqkvT + 131072, 256, 1024, r & 15, r >> 4, t, tile);
  } else if (bid < 3296) {
    // Wff1 [256][2048] -> Wff1T [2048][256]
    int r = bid - 3168;
    wt_tile64(Wff1, Wff1T, 256, 2048, r & 31, r >> 5, t, tile);
  } else {
    // Wff2 [1024][256] -> Wff2T [256][1024]
    int r = bid - 3296;
    wt_tile64(Wff2, Wff2T, 1024, 256, r & 3, r >> 2, t, tile);
  }
}

// ---------- fused qkv GEMM with fragment-layout epilogue ----------
// A = xt_bf [4096][256]; Bt = WqkvT [1536][256]. grid (24, 64).
__global__ __launch_bounds__(256) void k_gemm_qkv(const short* __restrict__ A, const short* __restrict__ Bt,
                                                  short* __restrict__ qfrag, short* __restrict__ kfrag,
                                                  short* __restrict__ vfrag) {
  __shared__ short As[2][2048];
  __shared__ short Bs[2][2048];
  __shared__ short Cs[64 * 72];
  int t = threadIdx.x;
  int bx = blockIdx.x, by = blockIdx.y;
  int sel = bx >> 3, h = bx & 7;
  int row0 = by * 64, col0 = bx * 64;
  int b = by >> 5, n0 = (by * 8) & 255;
  int bh = b * 8 + h;
  int w = t >> 6, lane = t & 63, quad = lane >> 4, l16 = lane & 15;
  int wr = w >> 1, wc = w & 1;
  int r = t >> 2;
  int cs = ((t & 3) ^ ((r >> 1) & 3)) * 8;
  const short* Ag = A + (size_t)(row0 + r) * 256 + cs;
  const short* Bg = Bt + (size_t)(col0 + r) * 256 + cs;
  int sw = (l16 >> 1) & 3;
  int chk = (quad ^ sw) * 8;
  int aoff[2], boff[2];
#pragma unroll
  for (int rf = 0; rf < 2; rf++) {
    aoff[rf] = (wr * 32 + rf * 16 + l16) * 32 + chk;
    boff[rf] = (wc * 32 + rf * 16 + l16) * 32 + chk;
  }
  f32x4 acc[2][2] = {{{0,0,0,0},{0,0,0,0}},{{0,0,0,0},{0,0,0,0}}};
  gload16(Ag, &As[0][w * 512]);
  gload16(Bg, &Bs[0][w * 512]);
  __syncthreads();
  int buf = 0;
  for (int k0 = 0; k0 < 256; k0 += 32) {
    int nb = buf ^ 1;
    if (k0 + 32 < 256) {
      gload16(Ag + k0 + 32, &As[nb][w * 512]);
      gload16(Bg + k0 + 32, &Bs[nb][w * 512]);
    }
    bf16x8 af[2], bf[2];
#pragma unroll
    for (int rf = 0; rf < 2; rf++) af[rf] = *(const bf16x8*)&As[buf][aoff[rf]];
#pragma unroll
    for (int cf = 0; cf < 2; cf++) bf[cf] = *(const bf16x8*)&Bs[buf][boff[cf]];
#pragma unroll
    for (int rf = 0; rf < 2; rf++)
#pragma unroll
      for (int cf = 0; cf < 2; cf++)
        acc[rf][cf] = __builtin_amdgcn_mfma_f32_16x16x32_bf16(af[rf], bf[cf], acc[rf][cf], 0, 0, 0);
    __syncthreads();
    buf = nb;
  }
  // ---- stage result tile to LDS as bf16 ----
  if (sel < 2) {
#pragma unroll
    for (int rf = 0; rf < 2; rf++)
#pragma unroll
      for (int cf = 0; cf < 2; cf++) {
        int col = wc * 32 + cf * 16 + l16;
#pragma unroll
        for (int rr = 0; rr < 4; rr++)
          Cs[(wr * 32 + rf * 16 + quad * 4 + rr) * 72 + col] = f2bf(acc[rf][cf][rr]);
      }
  } else {
#pragma unroll
    for (int rf = 0; rf < 2; rf++)
#pragma unroll
      for (int cf = 0; cf < 2; cf++) {
        int col = wc * 32 + cf * 16 + l16;
        bf16x4 pk;
#pragma unroll
        for (int rr = 0; rr < 4; rr++) pk[rr] = f2bf(acc[rf][cf][rr]);
        *(bf16x4*)&Cs[col * 72 + wr * 32 + rf * 16 + quad * 4] = pk;
      }
  }
  __syncthreads();
  // ---- fragment-order global writes ----
  if (sel < 2) {
    short* dst = sel ? kfrag : qfrag;
    int it = n0 >> 4, l16b = n0 & 8;
#pragma unroll
    for (int cidx = 0; cidx < 2; cidx++) {
      int chunk = t + cidx * 256;        // bits: m[8:6] ks[5] q2[4:3] n[2:0]
      int m = chunk >> 6, ks2 = (chunk >> 5) & 1, q2 = (chunk >> 3) & 3, n = chunk & 7;
      bf16x8 val = *(const bf16x8*)&Cs[(n * 8 + m) * 72 + ks2 * 32 + q2 * 8];
      size_t off = ((size_t)(bh * 128 + m * 16 + it) * 2 + ks2) * 512 + (q2 * 16 + l16b + n) * 8;
      *(bf16x8*)(dst + off) = val;
    }
  } else {
    int jc = n0 >> 5, jf = (n0 >> 4) & 1, qbase = (n0 & 8) >> 2;   // quad base 0 or 2
#pragma unroll
    for (int cidx = 0; cidx < 2; cidx++) {
      int chunk = t + cidx * 256;        // bits: qd[8] m0[7:6] dt[5:4] l16[3:0]
      int qd = chunk >> 8, m0 = (chunk >> 6) & 3, dtt = (chunk >> 4) & 3, l16c = chunk & 15;
      int d = dtt * 16 + l16c;
      unsigned u[4];
#pragma unroll
      for (int e3 = 0; e3 < 4; e3++)
        u[e3] = *(const unsigned*)&Cs[d * 72 + qd * 32 + e3 * 8 + 2 * m0];
      uint4 pv;
      pv.x = __builtin_amdgcn_perm(u[1], u[0], 0x05040100u);
      pv.y = __builtin_amdgcn_perm(u[3], u[2], 0x05040100u);
      pv.z = __builtin_amdgcn_perm(u[1], u[0], 0x07060302u);
      pv.w = __builtin_amdgcn_perm(u[3], u[2], 0x07060302u);
      int quad2 = qbase + qd;
      size_t cid = (((size_t)(bh * 8 + jc) * 4 + m0) * 4 + dtt) * 2 + jf;
      *(bf16x8*)(vfrag + cid * 512 + (quad2 * 16 + l16c) * 8) = __builtin_bit_cast(bf16x8, pv);
    }
  }
}

// ---------- bf16 MFMA GEMM with split-K; global_load_lds double-buffered main loop ----------
__global__ __launch_bounds__(256) void k_gemm_bf(const short* __restrict__ A, const short* __restrict__ Bt,
                                                 const float* __restrict__ bias, float* __restrict__ C,
                                                 int M, int N, int K, int Ks) {
  __shared__ short As[2][2048];
  __shared__ short Bs[2][2048];
  int t = threadIdx.x;
  int row0 = blockIdx.y * 64, col0 = blockIdx.x * 64;
  int kp = blockIdx.z;
  int kbeg = kp * Ks, kend = kbeg + Ks;
  int w = t >> 6, lane = t & 63, quad = lane >> 4, l16 = lane & 15;
  int wr = w >> 1, wc = w & 1;
  int r = t >> 2;
  int cs = ((t & 3) ^ ((r >> 1) & 3)) * 8;
  const short* Ag = A + (size_t)(row0 + r) * K + cs;
  const short* Bg = Bt + (size_t)(col0 + r) * K + cs;
  int sw = (l16 >> 1) & 3;
  int chk = (quad ^ sw) * 8;
  int aoff[2], boff[2];
#pragma unroll
  for (int rf = 0; rf < 2; rf++) {
    aoff[rf] = (wr * 32 + rf * 16 + l16) * 32 + chk;
    boff[rf] = (wc * 32 + rf * 16 + l16) * 32 + chk;
  }
  f32x4 acc[2][2] = {{{0,0,0,0},{0,0,0,0}},{{0,0,0,0},{0,0,0,0}}};
  gload16(Ag + kbeg, &As[0][w * 512]);
  gload16(Bg + kbeg, &Bs[0][w * 512]);
  __syncthreads();
  int buf = 0;
  for (int k0 = kbeg; k0 < kend; k0 += 32) {
    int nb = buf ^ 1;
    if (k0 + 32 < kend) {
      gload16(Ag + k0 + 32, &As[nb][w * 512]);
      gload16(Bg + k0 + 32, &Bs[nb][w * 512]);
    }
    bf16x8 af[2], bf[2];
#pragma unroll
    for (int rf = 0; rf < 2; rf++) af[rf] = *(const bf16x8*)&As[buf][aoff[rf]];
#pragma unroll
    for (int cf = 0; cf < 2; cf++) bf[cf] = *(const bf16x8*)&Bs[buf][boff[cf]];
#pragma unroll
    for (int rf = 0; rf < 2; rf++)
#pragma unroll
      for (int cf = 0; cf < 2; cf++)
        acc[rf][cf] = __builtin_amdgcn_mfma_f32_16x16x32_bf16(af[rf], bf[cf], acc[rf][cf], 0, 0, 0);
    __syncthreads();
    buf = nb;
  }
  float* Cp = C + (size_t)kp * M * N;
#pragma unroll
  for (int rf = 0; rf < 2; rf++)
#pragma unroll
    for (int cf = 0; cf < 2; cf++) {
      int col = col0 + wc * 32 + cf * 16 + l16;
      float vb = (bias && kp == 0) ? bias[col] : 0.0f;
#pragma unroll
      for (int rr = 0; rr < 4; rr++) {
        int row = row0 + wr * 32 + rf * 16 + quad * 4 + rr;
        Cp[(size_t)row * N + col] = acc[rf][cf][rr] + vb;
      }
    }
}

// ---------- fused ff1 GEMM + GEGLU ----------
__global__ __launch_bounds__(256) void k_ff1g(const short* __restrict__ A, const short* __restrict__ Bt,
                                              const float* __restrict__ bias, short* __restrict__ gg) {
  __shared__ short As[2][2048];
  __shared__ short Ba[2][2048];
  __shared__ short Bgs[2][2048];
  int t = threadIdx.x;
  int colA0 = blockIdx.x * 64, row0 = blockIdx.y * 64;
  int w = t >> 6, lane = t & 63, quad = lane >> 4, l16 = lane & 15;
  int wr = w >> 1, wc = w & 1;
  int r = t >> 2;
  int cs = ((t & 3) ^ ((r >> 1) & 3)) * 8;
  const short* Ag  = A + (size_t)(row0 + r) * 256 + cs;
  const short* Bpa = Bt + (size_t)(colA0 + r) * 256 + cs;
  const short* Bpg = Bt + (size_t)(1024 + colA0 + r) * 256 + cs;
  int sw = (l16 >> 1) & 3;
  int chk = (quad ^ sw) * 8;
  int aoff[2], boff[2];
#pragma unroll
  for (int rf = 0; rf < 2; rf++) {
    aoff[rf] = (wr * 32 + rf * 16 + l16) * 32 + chk;
    boff[rf] = (wc * 32 + rf * 16 + l16) * 32 + chk;
  }
  f32x4 za = {0, 0, 0, 0};
  f32x4 acc_a[2][2] = {{za, za}, {za, za}};
  f32x4 acc_g[2][2] = {{za, za}, {za, za}};
  gload16(Ag, &As[0][w * 512]);
  gload16(Bpa, &Ba[0][w * 512]);
  gload16(Bpg, &Bgs[0][w * 512]);
  __syncthreads();
  int buf = 0;
  for (int k0 = 0; k0 < 256; k0 += 32) {
    int nb = buf ^ 1;
    if (k0 + 32 < 256) {
      gload16(Ag + k0 + 32, &As[nb][w * 512]);
      gload16(Bpa + k0 + 32, &Ba[nb][w * 512]);
      gload16(Bpg + k0 + 32, &Bgs[nb][w * 512]);
    }
    bf16x8 af[2], ba[2], bg[2];
#pragma unroll
    for (int rf = 0; rf < 2; rf++) af[rf] = *(const bf16x8*)&As[buf][aoff[rf]];
#pragma unroll
    for (int cf = 0; cf < 2; cf++) {
      ba[cf] = *(const bf16x8*)&Ba[buf][boff[cf]];
      bg[cf] = *(const bf16x8*)&Bgs[buf][boff[cf]];
    }
#pragma unroll
    for (int rf = 0; rf < 2; rf++)
#pragma unroll
      for (int cf = 0; cf < 2; cf++) {
        acc_a[rf][cf] = __builtin_amdgcn_mfma_f32_16x16x32_bf16(af[rf], ba[cf], acc_a[rf][cf], 0, 0, 0);
        acc_g[rf][cf] = __builtin_amdgcn_mfma_f32_16x16x32_bf16(af[rf], bg[cf], acc_g[rf][cf], 0, 0, 0);
      }
    __syncthreads();
    buf = nb;
  }
#pragma unroll
  for (int rf = 0; rf < 2; rf++)
#pragma unroll
    for (int cf = 0; cf < 2; cf++) {
      int col = colA0 + wc * 32 + cf * 16 + l16;
      float ba_ = bias[col], bg_ = bias[1024 + col];
#pragma unroll
      for (int rr = 0; rr < 4; rr++) {
        int row = row0 + wr * 32 + rf * 16 + quad * 4 + rr;
        float a = acc_a[rf][cf][rr] + ba_;
        float g = acc_g[rf][cf][rr] + bg_;
        float ge = 0.5f * g * (1.0f + erff(g * 0.70710678118654752f));
        gg[(size_t)row * 1024 + col] = f2bf(a * ge);
      }
    }
}

// ---------- attention pass 1: XCD-swizzled flat grid 1024 ----------
__global__ __launch_bounds__(256) void k_attn_den5(const short* __restrict__ qfrag, const short* __restrict__ kfrag,
                                                   float* __restrict__ rdg) {
  int bid = blockIdx.x;
  int j = bid >> 3;
  int bh = ((bid & 7) << 1) + (j >> 6);
  int idx = j & 63;
  int ct2 = idx & 15, mp = idx >> 4;
  int t = threadIdx.x;
  int w = t >> 6, lane = t & 63;
  int rt0 = ct2 * 8 + w * 2;
  bf16x8 bfr[2][2];
#pragma unroll
  for (int cf = 0; cf < 2; cf++)
#pragma unroll
    for (int ks = 0; ks < 2; ks++)
      bfr[cf][ks] = *(const bf16x8*)(kfrag + ((size_t)((bh * 128 + rt0 + cf) * 2 + ks)) * 512 + lane * 8);
  for (int mi = 0; mi < 2; mi++) {
    int m = mp * 2 + mi;
    float fa0 = 0.0f, fa1 = 0.0f;
#pragma unroll 4
    for (int it2 = 0; it2 < 16; it2++) {
      const short* ap = qfrag + ((size_t)((bh * 128 + m * 16 + it2) * 2)) * 512 + lane * 8;
      bf16x8 a0 = *(const bf16x8*)ap;
      bf16x8 a1 = *(const bf16x8*)(ap + 512);
      f32x4 c0 = {0, 0, 0, 0}, c1 = {0, 0, 0, 0};
      c0 = __builtin_amdgcn_mfma_f32_16x16x32_bf16(a0, bfr[0][0], c0, 0, 0, 0);
      c0 = __builtin_amdgcn_mfma_f32_16x16x32_bf16(a1, bfr[0][1], c0, 0, 0, 0);
      c1 = __builtin_amdgcn_mfma_f32_16x16x32_bf16(a0, bfr[1][0], c1, 0, 0, 0);
      c1 = __builtin_amdgcn_mfma_f32_16x16x32_bf16(a1, bfr[1][1], c1, 0, 0, 0);
#pragma unroll
      for (int rr = 0; rr < 4; rr++) {
        fa0 += __builtin_amdgcn_exp2f(c0[rr] * KS_);
        fa1 += __builtin_amdgcn_exp2f(c1[rr] * KS_);
      }
    }
    fa0 += __shfl_xor(fa0, 16); fa0 += __shfl_xor(fa0, 32);
    fa1 += __shfl_xor(fa1, 16); fa1 += __shfl_xor(fa1, 32);
    if (lane < 16) {
      rdg[(size_t)(bh * 8 + m) * 2048 + rt0 * 16 + lane] = -__builtin_amdgcn_logf(fa0);
      rdg[(size_t)(bh * 8 + m) * 2048 + (rt0 + 1) * 16 + lane] = -__builtin_amdgcn_logf(fa1);
    }
  }
}

// ---------- attention pass 2: XCD-swizzled flat grid 1024; loads at point of use ----------
__global__ __launch_bounds__(256) void k_attn_out6(const short* __restrict__ qfrag, const short* __restrict__ kfrag,
                                                   const short* __restrict__ vfrag, const float* __restrict__ rdg,
                                                   short* __restrict__ ao) {
  __shared__ float red[4 * 64 * 17];
  int bid = blockIdx.x;
  int j = bid >> 3;
  int bh = ((bid & 7) << 1) + (j >> 6);
  int idx = j & 63;
  int z = idx & 7, itp = idx >> 3;
  int b = bh >> 3, h = bh & 7;
  int t = threadIdx.x, w = t >> 6, lane = t & 63, quad = lane >> 4, l16 = lane & 15;
  const float* rb = rdg + (size_t)bh * 16384;
  f32x4 z4 = {0, 0, 0, 0};
  bf16x8 qf[2][2][2];
#pragma unroll
  for (int iti = 0; iti < 2; iti++)
#pragma unroll
    for (int mm = 0; mm < 2; mm++)
#pragma unroll
      for (int ks = 0; ks < 2; ks++)
        qf[iti][mm][ks] = *(const bf16x8*)(qfrag +
            ((size_t)((bh * 128 + (2 * w + mm) * 16 + itp * 2 + iti) * 2 + ks)) * 512 + lane * 8);
  f32x4 acc[2][4];
#pragma unroll
  for (int iti = 0; iti < 2; iti++)
#pragma unroll
    for (int dt = 0; dt < 4; dt++) acc[iti][dt] = z4;
#pragma unroll 1
  for (int jc = 0; jc < 8; jc++) {
    bf16x8 vf[4][2], kf[2][2];
    float4 nv0[2], nv1[2];
#pragma unroll
    for (int dt = 0; dt < 4; dt++)
#pragma unroll
      for (int jf = 0; jf < 2; jf++)
        vf[dt][jf] = *(const bf16x8*)(vfrag + ((((size_t)(bh * 8 + jc) * 4 + w) * 4 + dt) * 2 + jf) * 512 + lane * 8);
#pragma unroll
    for (int jf = 0; jf < 2; jf++) {
      const short* kp = kfrag + ((size_t)((bh * 128 + z * 16 + jc * 2 + jf) * 2)) * 512 + lane * 8;
      kf[jf][0] = *(const bf16x8*)kp;
      kf[jf][1] = *(const bf16x8*)(kp + 512);
      nv0[jf] = *(const float4*)(rb + (size_t)(2 * w) * 2048 + z * 256 + jc * 32 + jf * 16 + quad * 4);
      nv1[jf] = *(const float4*)(rb + (size_t)(2 * w + 1) * 2048 + z * 256 + jc * 32 + jf * 16 + quad * 4);
    }
    float n0[2][4] = {{nv0[0].x, nv0[0].y, nv0[0].z, nv0[0].w}, {nv0[1].x, nv0[1].y, nv0[1].z, nv0[1].w}};
    float n1[2][4] = {{nv1[0].x, nv1[0].y, nv1[0].z, nv1[0].w}, {nv1[1].x, nv1[1].y, nv1[1].z, nv1[1].w}};
#pragma unroll
    for (int iti = 0; iti < 2; iti++) {
      f32x4 c[2][2] = {{z4, z4}, {z4, z4}};
#pragma unroll
      for (int jf = 0; jf < 2; jf++)
#pragma unroll
        for (int mm = 0; mm < 2; mm++) {
          c[jf][mm] = __builtin_amdgcn_mfma_f32_16x16x32_bf16(kf[jf][0], qf[iti][mm][0], c[jf][mm], 0, 0, 0);
          c[jf][mm] = __builtin_amdgcn_mfma_f32_16x16x32_bf16(kf[jf][1], qf[iti][mm][1], c[jf][mm], 0, 0, 0);
        }
      bf16x8 pf[2];
#pragma unroll
      for (int jf = 0; jf < 2; jf++) {
        unsigned u[8];
#pragma unroll
        for (int e = 0; e < 4; e++) {
          u[e]     = __builtin_bit_cast(unsigned, __builtin_amdgcn_exp2f(fmaf(c[jf][0][e], KS_, n0[jf][e]))) + 0x8000u;
          u[e + 4] = __builtin_bit_cast(unsigned, __builtin_amdgcn_exp2f(fmaf(c[jf][1][e], KS_, n1[jf][e]))) + 0x8000u;
        }
        uint4 pv;
        pv.x = __builtin_amdgcn_perm(u[1], u[0], 0x07060302u);
        pv.y = __builtin_amdgcn_perm(u[3], u[2], 0x07060302u);
        pv.z = __builtin_amdgcn_perm(u[5], u[4], 0x07060302u);
        pv.w = __builtin_amdgcn_perm(u[7], u[6], 0x07060302u);
        pf[jf] = __builtin_bit_cast(bf16x8, pv);
      }
#pragma unroll
      for (int dt = 0; dt < 4; dt++)
#pragma unroll
        for (int jf = 0; jf < 2; jf++)
          acc[iti][dt] = __builtin_amdgcn_mfma_f32_16x16x32_bf16(vf[dt][jf], pf[jf], acc[iti][dt], 0, 0, 0);
    }
  }
  for (int iti = 0; iti < 2; iti++) {
#pragma unroll
    for (int dt = 0; dt < 4; dt++)
#pragma unroll
      for (int rr = 0; rr < 4; rr++)
        red[w * 1088 + (dt * 16 + quad * 4 + rr) * 17 + l16] = acc[iti][dt][rr];
    __syncthreads();
    {
      int i = t >> 4, dg = t & 15;
      float s[4] = {0, 0, 0, 0};
#pragma unroll
      for (int w2 = 0; w2 < 4; w2++)
#pragma unroll
        for (int r2 = 0; r2 < 4; r2++)
          s[r2] += red[w2 * 1088 + (dg * 4 + r2) * 17 + i];
      bf16x4 ov;
#pragma unroll
      for (int r2 = 0; r2 < 4; r2++) ov[r2] = f2bf(s[r2]);
      *(bf16x4*)(ao + (size_t)((b * 256 + itp * 32 + iti * 16 + i) * 8 + z) * 512 + h * 64 + dg * 4) = ov;
    }
    __syncthreads();
  }
}

// ---------- fused residual(np split-K partials) + layernorm; optional bf16 copy ----------
__global__ __launch_bounds__(256) void k_ln(const float* __restrict__ X, const float* __restrict__ P, int np,
                                            const float* __restrict__ g, const float* __restrict__ be,
                                            float* __restrict__ Y, short* __restrict__ Ybf) {
  __shared__ float sm[8];
  int row = blockIdx.x, t = threadIdx.x;
  int lane = t & 63, w = t >> 6;
  size_t base = (size_t)row * 256;
  float v = X[base + t];
  for (int p = 0; p < np; p++) v += P[(size_t)p * 1048576 + base + t];
  float s = v;
  s += __shfl_xor(s, 1); s += __shfl_xor(s, 2); s += __shfl_xor(s, 4);
  s += __shfl_xor(s, 8); s += __shfl_xor(s, 16); s += __shfl_xor(s, 32);
  if (lane == 0) sm[w] = s;
  __syncthreads();
  float mu = (sm[0] + sm[1] + sm[2] + sm[3]) * (1.0f / 256.0f);
  float dv = v - mu;
  float s2 = dv * dv;
  s2 += __shfl_xor(s2, 1); s2 += __shfl_xor(s2, 2); s2 += __shfl_xor(s2, 4);
  s2 += __shfl_xor(s2, 8); s2 += __shfl_xor(s2, 16); s2 += __shfl_xor(s2, 32);
  if (lane == 0) sm[4 + w] = s2;
  __syncthreads();
  float var = (sm[4] + sm[5] + sm[6] + sm[7]) * (1.0f / 256.0f);
  float rs = rsqrtf(var + 1e-5f);
  float res = dv * rs * g[t] + be[t];
  Y[base + t] = res;
  if (Ybf) Ybf[base + t] = f2bf(res);
}

extern "C" void kernel_launch(void* const* d_in, const int* in_sizes, int n_in,
                              void* d_out, int out_size, void* d_ws, size_t ws_size,
                              hipStream_t stream) {
  const float* x    = (const float*)d_in[0];
  const float* Wq   = (const float*)d_in[1];
  const float* Wkv  = (const float*)d_in[2];
  const float* Wout = (const float*)d_in[3];
  const float* bout = (const float*)d_in[4];
  const float* g1   = (const float*)d_in[5];
  const float* be1  = (const float*)d_in[6];
  const float* Wff1 = (const float*)d_in[7];
  const float* bff1 = (const float*)d_in[8];
  const float* Wff2 = (const float*)d_in[9];
  const float* bff2 = (const float*)d_in[10];
  const float* g2   = (const float*)d_in[11];
  const float* be2  = (const float*)d_in[12];
  float* out = (float*)d_out;
  float* w = (float*)d_ws;

  // fp32 zone
  float* xt   = w;              // 1,048,576
  float* part = w + 1048576;    // split-K partials (4 x 1M, two phases)
  float* y    = w + 9437184;    // 1,048,576
  float* rdg  = w + 11534336;   //   262,144  -log2(den), [bh*8+m][2048]
  // bf16 zone
  short* sb     = (short*)(w + 11796480);
  short* qfrag  = sb;                    // 2,097,152
  short* kfrag  = sb + 2097152;          // 2,097,152
  short* vfrag  = sb + 4194304;          // 2,097,152
  short* xt_bf  = sb + 6291456;          // 1,048,576
  short* ao_bf  = sb + 7340032;          // 2,097,152
  short* y_bf   = sb + 9437184;          // 1,048,576
  short* gg_bf  = sb + 10485760;         // 4,194,304
  short* WqkvT  = sb + 14680064;         //   393,216  [1536][256]
  short* WoutT  = sb + 15073280;         // 8,388,608
  short* Wff1T  = sb + 23461888;         //   524,288
  short* Wff2T  = sb + 23986176;         //   262,144

  k_prep_all<<<3360, 256, 0, stream>>>(x, xt, xt_bf, Wq, Wkv, Wout, Wff1, Wff2,
                                       WqkvT, WoutT, Wff1T, Wff2T);
  k_gemm_qkv<<<dim3(24, 64), 256, 0, stream>>>(xt_bf, WqkvT, qfrag, kfrag, vfrag);
  k_attn_den5<<<1024, 256, 0, stream>>>(qfrag, kfrag, rdg);
  k_attn_out6<<<1024, 256, 0, stream>>>(qfrag, kfrag, vfrag, rdg, ao_bf);
  k_gemm_bf<<<dim3(32, 8, 4), 256, 0, stream>>>(ao_bf, WoutT, bout, part, 512, 2048, 4096, 1024);
  k_ln<<<4096, 256, 0, stream>>>(xt, part, 4, g1, be1, y, y_bf);
  k_ff1g<<<dim3(16, 64), 256, 0, stream>>>(y_bf, Wff1T, bff1, gg_bf);
  k_gemm_bf<<<dim3(4, 64, 4), 256, 0, stream>>>(gg_bf, Wff2T, bff2, part, 4096, 256, 1024, 256);
  k_ln<<<4096, 256, 0, stream>>>(y, part, 4, g2, be2, out, nullptr);
}